// Round 1
// baseline (1174.144 us; speedup 1.0000x reference)
//
#include <hip/hip_runtime.h>
#include <math.h>

// Problem constants: B=2, N=2048, D=1024, H=16, HD=64, C=4
// ws layout (floats): q[4194304] k[4194304] v[4194304] o[4194304] rowscale[4096]

// ---------------------------------------------------------------------------
// GEMM  C[M,x] = A[M,1024] * B[x,1024]^T  (both K-major, NT)
// BM=BN=128, BK=16, 256 threads, 8x8 per thread (4+4 split halves 64 apart).
// MODE 0: scatter epilogue into q/k/v (B,H,N,HD).  MODE 1: plain row-major C0.
// ---------------------------------------------------------------------------
template<int MODE>
__global__ __launch_bounds__(256)
void gemm_nt(const float* __restrict__ A, const float* __restrict__ Bm,
             float* __restrict__ C0, float* __restrict__ C1, float* __restrict__ C2)
{
    __shared__ __align__(16) float As[16][132];
    __shared__ __align__(16) float Bs[16][132];
    const int t    = threadIdx.x;
    const int m0   = blockIdx.y * 128;
    const int n0   = blockIdx.x * 128;
    const int trow = t >> 4;      // 0..15
    const int tcol = t & 15;      // 0..15

    float acc[8][8];
#pragma unroll
    for (int i = 0; i < 8; i++)
#pragma unroll
        for (int j = 0; j < 8; j++) acc[i][j] = 0.f;

    const int lr = t >> 2;         // 0..63
    const int lc = (t & 3) * 4;    // 0,4,8,12
    const float* ap0 = A  + (size_t)(m0 + lr) * 1024 + lc;
    const float* ap1 = A  + (size_t)(m0 + 64 + lr) * 1024 + lc;
    const float* bp0 = Bm + (size_t)(n0 + lr) * 1024 + lc;
    const float* bp1 = Bm + (size_t)(n0 + 64 + lr) * 1024 + lc;

    for (int k0 = 0; k0 < 1024; k0 += 16) {
        float4 a0 = *(const float4*)(ap0 + k0);
        float4 a1 = *(const float4*)(ap1 + k0);
        float4 b0 = *(const float4*)(bp0 + k0);
        float4 b1 = *(const float4*)(bp1 + k0);
        __syncthreads();
        As[lc+0][lr]    = a0.x; As[lc+1][lr]    = a0.y; As[lc+2][lr]    = a0.z; As[lc+3][lr]    = a0.w;
        As[lc+0][64+lr] = a1.x; As[lc+1][64+lr] = a1.y; As[lc+2][64+lr] = a1.z; As[lc+3][64+lr] = a1.w;
        Bs[lc+0][lr]    = b0.x; Bs[lc+1][lr]    = b0.y; Bs[lc+2][lr]    = b0.z; Bs[lc+3][lr]    = b0.w;
        Bs[lc+0][64+lr] = b1.x; Bs[lc+1][64+lr] = b1.y; Bs[lc+2][64+lr] = b1.z; Bs[lc+3][64+lr] = b1.w;
        __syncthreads();
#pragma unroll
        for (int kk = 0; kk < 16; kk++) {
            float4 alo = *(const float4*)&As[kk][trow*4];
            float4 ahi = *(const float4*)&As[kk][64+trow*4];
            float4 blo = *(const float4*)&Bs[kk][tcol*4];
            float4 bhi = *(const float4*)&Bs[kk][64+tcol*4];
            float a[8]  = {alo.x,alo.y,alo.z,alo.w, ahi.x,ahi.y,ahi.z,ahi.w};
            float bb[8] = {blo.x,blo.y,blo.z,blo.w, bhi.x,bhi.y,bhi.z,bhi.w};
#pragma unroll
            for (int i = 0; i < 8; i++)
#pragma unroll
                for (int j = 0; j < 8; j++)
                    acc[i][j] = fmaf(a[i], bb[j], acc[i][j]);
        }
    }

#pragma unroll
    for (int ih = 0; ih < 2; ih++)
#pragma unroll
    for (int i = 0; i < 4; i++) {
        const int m = m0 + ih*64 + trow*4 + i;
#pragma unroll
        for (int jh = 0; jh < 2; jh++) {
            const int col = n0 + jh*64 + tcol*4;
            float4 v = make_float4(acc[ih*4+i][jh*4+0], acc[ih*4+i][jh*4+1],
                                   acc[ih*4+i][jh*4+2], acc[ih*4+i][jh*4+3]);
            if (MODE == 0) {
                const int b = m >> 11, n = m & 2047;
                const int which = col >> 10, rem = col & 1023;
                const int h = rem >> 6, hd = rem & 63;
                float* dst = (which == 0 ? C0 : (which == 1 ? C1 : C2));
                *(float4*)(dst + ((((size_t)b*16 + h)*2048 + n)*64 + hd)) = v;
            } else {
                *(float4*)(C0 + (size_t)m * 1024 + col) = v;
            }
        }
    }
}

// ---------------------------------------------------------------------------
// RMSNorm over last dim 64, in place.  One wave per row. rows = B*H*N = 65536.
// ---------------------------------------------------------------------------
__global__ __launch_bounds__(256)
void rmsnorm_k(float* __restrict__ t, const float* __restrict__ w)
{
    const int row  = blockIdx.x * 4 + (threadIdx.x >> 6);
    const int lane = threadIdx.x & 63;
    const size_t idx = (size_t)row * 64 + lane;
    float v = t[idx];
    float s = v * v;
#pragma unroll
    for (int off = 32; off; off >>= 1) s += __shfl_xor(s, off);
    float sc = rsqrtf(s * (1.0f/64.0f) + 1e-6f);
    t[idx] = v * sc * w[lane];
}

// ---------------------------------------------------------------------------
// rowscale[b,q] = 1 / max(max_k dot4(cm[b,:,q], cm[b,:,k]), 1e-6)
// grid = B * N/64 = 64 blocks, 256 threads: 64 q/block, 4 threads per q.
// ---------------------------------------------------------------------------
__global__ __launch_bounds__(256)
void rowscale_k(const float* __restrict__ cm, float* __restrict__ rs)
{
    __shared__ float cms[4][2048];
    const int b  = blockIdx.x >> 5;
    const int qt = blockIdx.x & 31;
    const float* base = cm + (size_t)b * 4 * 2048;
    for (int i = threadIdx.x; i < 2048; i += 256) {
        cms[0][i] = base[i];
        cms[1][i] = base[2048 + i];
        cms[2][i] = base[4096 + i];
        cms[3][i] = base[6144 + i];
    }
    __syncthreads();
    const int q    = qt * 64 + (threadIdx.x >> 2);
    const int part = threadIdx.x & 3;
    const float a0 = cms[0][q], a1 = cms[1][q], a2 = cms[2][q], a3 = cms[3][q];
    float mx = 0.f;
    for (int i = 0; i < 512; i++) {
        const int k = part + 4 * i;   // interleaved -> conflict-free
        float d = a0*cms[0][k] + a1*cms[1][k] + a2*cms[2][k] + a3*cms[3][k];
        mx = fmaxf(mx, d);
    }
    mx = fmaxf(mx, __shfl_xor(mx, 1));
    mx = fmaxf(mx, __shfl_xor(mx, 2));
    if (part == 0) rs[b * 2048 + q] = 1.0f / fmaxf(mx, 1e-6f);
}

// ---------------------------------------------------------------------------
// Flash attention with fused bias.
// Block = (b, h, 64-row q tile); 256 threads as 16x16; 4x4 frags; 64-wide k tiles.
// logits = (q.k)*0.125 + g3 * ((same*rsq - 0.5)*2 + 0.3*im)
// ---------------------------------------------------------------------------
__global__ __launch_bounds__(256)
void attn_k(const float* __restrict__ Q, const float* __restrict__ Kt,
            const float* __restrict__ V, const float* __restrict__ cm,
            const float* __restrict__ im, const float* __restrict__ rs,
            const float* __restrict__ gate, float* __restrict__ O)
{
    const int bid = blockIdx.x;
    const int h  = bid & 15;
    const int qt = (bid >> 4) & 31;
    const int b  = bid >> 9;

    __shared__ __align__(16) float Qs[64][68];   // [d][q]
    __shared__ __align__(16) float Ks[64][68];   // [d][k]
    __shared__ __align__(16) float Vs[64][68];   // [k][d]
    __shared__ __align__(16) float Ps[64][68];   // [k][q]
    __shared__ float cmk[4][64];

    const int t    = threadIdx.x;
    const int trow = t >> 4;            // 0..15
    const int tcol = t & 15;            // 0..15
    const int tq0  = trow * 4;          // q-frag offset
    const int tk0  = tcol * 4;          // k-frag / d-frag offset

    const size_t headoff = ((size_t)(b*16 + h)) * 2048 * 64;
    const float* Qh = Q  + headoff + (size_t)qt * 64 * 64;
    const float* Kh = Kt + headoff;
    const float* Vh = V  + headoff;
    const float* cmb = cm + (size_t)b * 4 * 2048;
    const float* imb = im + ((size_t)b * 2048 + (size_t)qt * 64) * 2048;

    // load Q tile transposed
    for (int i = t; i < 1024; i += 256) {
        const int r  = i >> 4;
        const int c4 = (i & 15) * 4;
        float4 f = *(const float4*)(Qh + (size_t)r * 64 + c4);
        Qs[c4+0][r] = f.x; Qs[c4+1][r] = f.y; Qs[c4+2][r] = f.z; Qs[c4+3][r] = f.w;
    }

    float g = gate[h];
    g = fminf(fmaxf(g, 0.f), 1.f);
    const float g3 = g * 3.0f;

    float cq[4][4], rsq[4];
#pragma unroll
    for (int i = 0; i < 4; i++) {
        const int qg = qt*64 + tq0 + i;
        rsq[i] = rs[b*2048 + qg];
#pragma unroll
        for (int c = 0; c < 4; c++) cq[c][i] = cmb[c*2048 + qg];
    }

    float mi[4], li[4], o[4][4];
#pragma unroll
    for (int i = 0; i < 4; i++) {
        mi[i] = -INFINITY; li[i] = 0.f;
#pragma unroll
        for (int j = 0; j < 4; j++) o[i][j] = 0.f;
    }

    for (int kt = 0; kt < 32; kt++) {
        const int kbase = kt * 64;
        __syncthreads();   // prev PV / Qs-load drained before overwriting K/V/Ps
        for (int i = t; i < 1024; i += 256) {
            const int r  = i >> 4;
            const int c4 = (i & 15) * 4;
            float4 f  = *(const float4*)(Kh + (size_t)(kbase + r) * 64 + c4);
            Ks[c4+0][r] = f.x; Ks[c4+1][r] = f.y; Ks[c4+2][r] = f.z; Ks[c4+3][r] = f.w;
            float4 g4 = *(const float4*)(Vh + (size_t)(kbase + r) * 64 + c4);
            *(float4*)&Vs[r][c4] = g4;
        }
        if (t < 64) {
#pragma unroll
            for (int c = 0; c < 4; c++) cmk[c][t] = cmb[c*2048 + kbase + t];
        }
        float im4[4][4];
#pragma unroll
        for (int i = 0; i < 4; i++) {
            float4 f = *(const float4*)(imb + (size_t)(tq0 + i) * 2048 + kbase + tk0);
            im4[i][0] = f.x; im4[i][1] = f.y; im4[i][2] = f.z; im4[i][3] = f.w;
        }
        __syncthreads();

        // S = Q . K^T
        float s[4][4];
#pragma unroll
        for (int i = 0; i < 4; i++)
#pragma unroll
            for (int j = 0; j < 4; j++) s[i][j] = 0.f;
        for (int d = 0; d < 64; d++) {
            float4 qf = *(const float4*)&Qs[d][tq0];
            float4 kf = *(const float4*)&Ks[d][tk0];
            float qa[4] = {qf.x, qf.y, qf.z, qf.w};
            float ka[4] = {kf.x, kf.y, kf.z, kf.w};
#pragma unroll
            for (int i = 0; i < 4; i++)
#pragma unroll
                for (int j = 0; j < 4; j++)
                    s[i][j] = fmaf(qa[i], ka[j], s[i][j]);
        }

        float ck[4][4];
#pragma unroll
        for (int c = 0; c < 4; c++)
#pragma unroll
            for (int j = 0; j < 4; j++) ck[c][j] = cmk[c][tk0 + j];

#pragma unroll
        for (int i = 0; i < 4; i++) {
            float sr[4];
#pragma unroll
            for (int j = 0; j < 4; j++) {
                float same = cq[0][i]*ck[0][j] + cq[1][i]*ck[1][j]
                           + cq[2][i]*ck[2][j] + cq[3][i]*ck[3][j];
                float bias = (same * rsq[i] - 0.5f) * 2.0f + 0.3f * im4[i][j];
                sr[j] = s[i][j] * 0.125f + g3 * bias;
            }
            float rmax = fmaxf(fmaxf(sr[0], sr[1]), fmaxf(sr[2], sr[3]));
            rmax = fmaxf(rmax, __shfl_xor(rmax, 1));
            rmax = fmaxf(rmax, __shfl_xor(rmax, 2));
            rmax = fmaxf(rmax, __shfl_xor(rmax, 4));
            rmax = fmaxf(rmax, __shfl_xor(rmax, 8));
            const float mnew  = fmaxf(mi[i], rmax);
            const float alpha = __expf(mi[i] - mnew);
            float p[4], rsum = 0.f;
#pragma unroll
            for (int j = 0; j < 4; j++) { p[j] = __expf(sr[j] - mnew); rsum += p[j]; }
            rsum += __shfl_xor(rsum, 1);
            rsum += __shfl_xor(rsum, 2);
            rsum += __shfl_xor(rsum, 4);
            rsum += __shfl_xor(rsum, 8);
            li[i] = li[i] * alpha + rsum;
            mi[i] = mnew;
#pragma unroll
            for (int j = 0; j < 4; j++) o[i][j] *= alpha;
            Ps[tk0+0][tq0+i] = p[0];
            Ps[tk0+1][tq0+i] = p[1];
            Ps[tk0+2][tq0+i] = p[2];
            Ps[tk0+3][tq0+i] = p[3];
        }
        __syncthreads();

        // O += P . V
        for (int k = 0; k < 64; k++) {
            float4 pf = *(const float4*)&Ps[k][tq0];
            float4 vf = *(const float4*)&Vs[k][tk0];
            float pa[4] = {pf.x, pf.y, pf.z, pf.w};
            float va[4] = {vf.x, vf.y, vf.z, vf.w};
#pragma unroll
            for (int i = 0; i < 4; i++)
#pragma unroll
                for (int j = 0; j < 4; j++)
                    o[i][j] = fmaf(pa[i], va[j], o[i][j]);
        }
    }

#pragma unroll
    for (int i = 0; i < 4; i++) {
        const int qg = qt*64 + tq0 + i;
        const float inv = 1.0f / li[i];
        float4 v = make_float4(o[i][0]*inv, o[i][1]*inv, o[i][2]*inv, o[i][3]*inv);
        *(float4*)(O + ((size_t)b*2048 + qg) * 1024 + h*64 + tk0) = v;
    }
}

// ---------------------------------------------------------------------------
extern "C" void kernel_launch(void* const* d_in, const int* in_sizes, int n_in,
                              void* d_out, int out_size, void* d_ws, size_t ws_size,
                              hipStream_t stream)
{
    const float* x    = (const float*)d_in[0];
    const float* cm   = (const float*)d_in[1];
    const float* im   = (const float*)d_in[2];
    const float* Wqkv = (const float*)d_in[3];
    const float* Wout = (const float*)d_in[4];
    const float* qw   = (const float*)d_in[5];
    const float* kw   = (const float*)d_in[6];
    const float* gate = (const float*)d_in[7];
    float* out = (float*)d_out;

    float* ws = (float*)d_ws;
    float* qb = ws;                   // (B,H,N,HD)
    float* kb = qb + 4194304;
    float* vb = kb + 4194304;
    float* ob = vb + 4194304;         // (B,N,D)
    float* rsbuf = ob + 4194304;      // (B,N)

    // qkv projection + head scatter
    gemm_nt<0><<<dim3(24, 32), 256, 0, stream>>>(x, Wqkv, qb, kb, vb);
    // rmsnorm q, k
    rmsnorm_k<<<16384, 256, 0, stream>>>(qb, qw);
    rmsnorm_k<<<16384, 256, 0, stream>>>(kb, kw);
    // per-(b,q) row-max of char co-membership
    rowscale_k<<<64, 256, 0, stream>>>(cm, rsbuf);
    // flash attention with fused bias
    attn_k<<<1024, 256, 0, stream>>>(qb, kb, vb, cm, im, rsbuf, gate, ob);
    // output projection
    gemm_nt<1><<<dim3(8, 32), 256, 0, stream>>>(ob, Wout, out, nullptr, nullptr);
}

// Round 2
// 1042.592 us; speedup vs baseline: 1.1262x; 1.1262x over previous
//
#include <hip/hip_runtime.h>
#include <math.h>

// Problem constants: B=2, N=2048, D=1024, H=16, HD=64, C=4
// ws layout (floats): q[4194304] k[4194304] v[4194304] o[4194304] rowscale[4096]

typedef __attribute__((ext_vector_type(8))) short s8v;
typedef __attribute__((ext_vector_type(4))) short s4v;
typedef __attribute__((ext_vector_type(4))) float f4v;

__device__ __forceinline__ unsigned short f2bf(float x) {
    union { float f; unsigned u; } v; v.f = x;
    unsigned r = v.u + 0x7FFF + ((v.u >> 16) & 1);
    return (unsigned short)(r >> 16);
}
__device__ __forceinline__ float bf2f(unsigned short h) {
    union { unsigned u; float f; } v; v.u = ((unsigned)h) << 16;
    return v.f;
}
__device__ __forceinline__ f4v mfma16(s8v a, s8v b, f4v c) {
    return __builtin_amdgcn_mfma_f32_16x16x32_bf16(a, b, c, 0, 0, 0);
}

// ---------------------------------------------------------------------------
// GEMM  C[M,x] = A[M,1024] * B[x,1024]^T  (fp32 vector; unchanged, passing)
// ---------------------------------------------------------------------------
template<int MODE>
__global__ __launch_bounds__(256)
void gemm_nt(const float* __restrict__ A, const float* __restrict__ Bm,
             float* __restrict__ C0, float* __restrict__ C1, float* __restrict__ C2)
{
    __shared__ __align__(16) float As[16][132];
    __shared__ __align__(16) float Bs[16][132];
    const int t    = threadIdx.x;
    const int m0   = blockIdx.y * 128;
    const int n0   = blockIdx.x * 128;
    const int trow = t >> 4;
    const int tcol = t & 15;

    float acc[8][8];
#pragma unroll
    for (int i = 0; i < 8; i++)
#pragma unroll
        for (int j = 0; j < 8; j++) acc[i][j] = 0.f;

    const int lr = t >> 2;
    const int lc = (t & 3) * 4;
    const float* ap0 = A  + (size_t)(m0 + lr) * 1024 + lc;
    const float* ap1 = A  + (size_t)(m0 + 64 + lr) * 1024 + lc;
    const float* bp0 = Bm + (size_t)(n0 + lr) * 1024 + lc;
    const float* bp1 = Bm + (size_t)(n0 + 64 + lr) * 1024 + lc;

    for (int k0 = 0; k0 < 1024; k0 += 16) {
        float4 a0 = *(const float4*)(ap0 + k0);
        float4 a1 = *(const float4*)(ap1 + k0);
        float4 b0 = *(const float4*)(bp0 + k0);
        float4 b1 = *(const float4*)(bp1 + k0);
        __syncthreads();
        As[lc+0][lr]    = a0.x; As[lc+1][lr]    = a0.y; As[lc+2][lr]    = a0.z; As[lc+3][lr]    = a0.w;
        As[lc+0][64+lr] = a1.x; As[lc+1][64+lr] = a1.y; As[lc+2][64+lr] = a1.z; As[lc+3][64+lr] = a1.w;
        Bs[lc+0][lr]    = b0.x; Bs[lc+1][lr]    = b0.y; Bs[lc+2][lr]    = b0.z; Bs[lc+3][lr]    = b0.w;
        Bs[lc+0][64+lr] = b1.x; Bs[lc+1][64+lr] = b1.y; Bs[lc+2][64+lr] = b1.z; Bs[lc+3][64+lr] = b1.w;
        __syncthreads();
#pragma unroll
        for (int kk = 0; kk < 16; kk++) {
            float4 alo = *(const float4*)&As[kk][trow*4];
            float4 ahi = *(const float4*)&As[kk][64+trow*4];
            float4 blo = *(const float4*)&Bs[kk][tcol*4];
            float4 bhi = *(const float4*)&Bs[kk][64+tcol*4];
            float a[8]  = {alo.x,alo.y,alo.z,alo.w, ahi.x,ahi.y,ahi.z,ahi.w};
            float bb[8] = {blo.x,blo.y,blo.z,blo.w, bhi.x,bhi.y,bhi.z,bhi.w};
#pragma unroll
            for (int i = 0; i < 8; i++)
#pragma unroll
                for (int j = 0; j < 8; j++)
                    acc[i][j] = fmaf(a[i], bb[j], acc[i][j]);
        }
    }

#pragma unroll
    for (int ih = 0; ih < 2; ih++)
#pragma unroll
    for (int i = 0; i < 4; i++) {
        const int m = m0 + ih*64 + trow*4 + i;
#pragma unroll
        for (int jh = 0; jh < 2; jh++) {
            const int col = n0 + jh*64 + tcol*4;
            float4 v = make_float4(acc[ih*4+i][jh*4+0], acc[ih*4+i][jh*4+1],
                                   acc[ih*4+i][jh*4+2], acc[ih*4+i][jh*4+3]);
            if (MODE == 0) {
                const int b = m >> 11, n = m & 2047;
                const int which = col >> 10, rem = col & 1023;
                const int h = rem >> 6, hd = rem & 63;
                float* dst = (which == 0 ? C0 : (which == 1 ? C1 : C2));
                *(float4*)(dst + ((((size_t)b*16 + h)*2048 + n)*64 + hd)) = v;
            } else {
                *(float4*)(C0 + (size_t)m * 1024 + col) = v;
            }
        }
    }
}

// ---------------------------------------------------------------------------
// RMSNorm over last dim 64, in place.
// ---------------------------------------------------------------------------
__global__ __launch_bounds__(256)
void rmsnorm_k(float* __restrict__ t, const float* __restrict__ w)
{
    const int row  = blockIdx.x * 4 + (threadIdx.x >> 6);
    const int lane = threadIdx.x & 63;
    const size_t idx = (size_t)row * 64 + lane;
    float v = t[idx];
    float s = v * v;
#pragma unroll
    for (int off = 32; off; off >>= 1) s += __shfl_xor(s, off);
    float sc = rsqrtf(s * (1.0f/64.0f) + 1e-6f);
    t[idx] = v * sc * w[lane];
}

// ---------------------------------------------------------------------------
// rowscale[b,q] = 1 / max(max_k dot4(cm[b,:,q], cm[b,:,k]), 1e-6)
// ---------------------------------------------------------------------------
__global__ __launch_bounds__(256)
void rowscale_k(const float* __restrict__ cm, float* __restrict__ rs)
{
    __shared__ float cms[4][2048];
    const int b  = blockIdx.x >> 5;
    const int qt = blockIdx.x & 31;
    const float* base = cm + (size_t)b * 4 * 2048;
    for (int i = threadIdx.x; i < 2048; i += 256) {
        cms[0][i] = base[i];
        cms[1][i] = base[2048 + i];
        cms[2][i] = base[4096 + i];
        cms[3][i] = base[6144 + i];
    }
    __syncthreads();
    const int q    = qt * 64 + (threadIdx.x >> 2);
    const int part = threadIdx.x & 3;
    const float a0 = cms[0][q], a1 = cms[1][q], a2 = cms[2][q], a3 = cms[3][q];
    float mx = 0.f;
    for (int i = 0; i < 512; i++) {
        const int k = part + 4 * i;
        float d = a0*cms[0][k] + a1*cms[1][k] + a2*cms[2][k] + a3*cms[3][k];
        mx = fmaxf(mx, d);
    }
    mx = fmaxf(mx, __shfl_xor(mx, 1));
    mx = fmaxf(mx, __shfl_xor(mx, 2));
    if (part == 0) rs[b * 2048 + q] = 1.0f / fmaxf(mx, 1e-6f);
}

// ---------------------------------------------------------------------------
// Flash attention via MFMA bf16 hi/lo split (3-term products, ~fp32 accuracy).
// Block = (b, h, 128-q tile). 4 waves, each owns 32 q rows (2 m-tiles of 16).
// K-tiles of 64 keys. Softmax in log2 domain. 2 barriers per k-tile.
//
// Layouts (guide-verified, 16x16x32 bf16):
//   A-frag: A[m=lane&15][k=(lane>>4)*8+j]   (8 contiguous k per lane)
//   B-frag: B[k=(lane>>4)*8+j][n=lane&15]
//   C/D   : row=(lane>>4)*4+reg, col=lane&15
// LDS rows padded to 72 shorts -> frag b128 reads are 2-way-conflict (free).
// ---------------------------------------------------------------------------
#define L2E 1.44269504088896340736f

__global__ __launch_bounds__(256, 2)
void attn_mfma(const float* __restrict__ Q, const float* __restrict__ K,
               const float* __restrict__ V, const float* __restrict__ cm,
               const float* __restrict__ im, const float* __restrict__ rs,
               const float* __restrict__ gate, float* __restrict__ O)
{
    const int bid = blockIdx.x;
    const int h  = bid & 15;            // h fastest: 16 heads share im rows in L2
    const int qt = (bid >> 4) & 15;
    const int b  = bid >> 8;

    __shared__ __align__(16) short Ksh_h[64*72], Ksh_l[64*72];
    __shared__ __align__(16) short Vt_h[64*72],  Vt_l[64*72];
    __shared__ __align__(16) short Ps_h[128*72], Ps_l[128*72];
    __shared__ float cmk[4][64];

    const int t    = threadIdx.x;
    const int w    = t >> 6;
    const int lane = t & 63;
    const int col  = lane & 15;
    const int quad = lane >> 4;

    const size_t headoff = ((size_t)(b*16 + h)) * 2048 * 64;
    const float* Qh  = Q + headoff;
    const float* Kh  = K + headoff;
    const float* Vh  = V + headoff;
    const float* cmb = cm + (size_t)b * 8192;

    const int qbase = qt*128 + w*32;

    // ---- Q fragments (hi/lo) in registers for the whole K loop ----
    s8v qh[2][2], ql[2][2];
#pragma unroll
    for (int m = 0; m < 2; m++)
#pragma unroll
    for (int c = 0; c < 2; c++) {
        const float* p = Qh + (size_t)(qbase + m*16 + col)*64 + c*32 + quad*8;
        float4 f0 = *(const float4*)(p);
        float4 f1 = *(const float4*)(p + 4);
        float fv[8] = {f0.x,f0.y,f0.z,f0.w, f1.x,f1.y,f1.z,f1.w};
        s8v hi, lo;
#pragma unroll
        for (int j = 0; j < 8; j++) {
            unsigned short hb = f2bf(fv[j]);
            hi[j] = (short)hb;
            lo[j] = (short)f2bf(fv[j] - bf2f(hb));
        }
        qh[m][c] = hi; ql[m][c] = lo;
    }

    // ---- bias coefficients (log2 domain) ----
    float g = fminf(fmaxf(gate[h], 0.f), 1.f);
    const float g3L = 3.0f * g * L2E;
    const float cS  = 0.125f * L2E;
    const float cIm = 0.3f * g3L;
    const float cC  = -g3L;
    float aco[2][4];            // 2*rsq*g3*L2E per owned row
    float cq[4][2][4];          // character masks for owned q rows
#pragma unroll
    for (int m = 0; m < 2; m++)
#pragma unroll
    for (int reg = 0; reg < 4; reg++) {
        const int qg = qbase + m*16 + quad*4 + reg;
        aco[m][reg] = 2.0f * rs[b*2048 + qg] * g3L;
#pragma unroll
        for (int c = 0; c < 4; c++) cq[c][m][reg] = cmb[c*2048 + qg];
    }
    const float* imb = im + ((size_t)b*2048 + qbase)*2048 + col;  // + row*2048 + k

    float mi[2][4], li[2][4];
    f4v  Oa[2][4];
#pragma unroll
    for (int m = 0; m < 2; m++)
#pragma unroll
    for (int reg = 0; reg < 4; reg++) {
        mi[m][reg] = -INFINITY; li[m][reg] = 0.f;
    }
#pragma unroll
    for (int m = 0; m < 2; m++)
#pragma unroll
    for (int n = 0; n < 4; n++) { f4v z = {0.f,0.f,0.f,0.f}; Oa[m][n] = z; }

    for (int kt = 0; kt < 32; kt++) {
        const int kbase = kt * 64;
        __syncthreads();           // all waves done reading previous K/V tile
        // ---- stage K (row-major) and V (transposed) as bf16 hi/lo ----
        {
            const int key  = t >> 2;
            const int dsub = (t & 3) * 4;
            const float* kp = Kh + (size_t)(kbase + key)*64 + dsub;
            const float* vp = Vh + (size_t)(kbase + key)*64 + dsub;
#pragma unroll
            for (int i = 0; i < 4; i++) {
                float4 f = *(const float4*)(kp + i*16);
                float fa[4] = {f.x,f.y,f.z,f.w};
                s4v hv, lv;
#pragma unroll
                for (int j = 0; j < 4; j++) {
                    unsigned short hb = f2bf(fa[j]);
                    hv[j] = (short)hb;
                    lv[j] = (short)f2bf(fa[j] - bf2f(hb));
                }
                *(s4v*)&Ksh_h[key*72 + dsub + i*16] = hv;
                *(s4v*)&Ksh_l[key*72 + dsub + i*16] = lv;
                float4 gv = *(const float4*)(vp + i*16);
                float ga[4] = {gv.x,gv.y,gv.z,gv.w};
#pragma unroll
                for (int j = 0; j < 4; j++) {
                    unsigned short hb = f2bf(ga[j]);
                    Vt_h[(dsub + i*16 + j)*72 + key] = (short)hb;
                    Vt_l[(dsub + i*16 + j)*72 + key] = (short)f2bf(ga[j] - bf2f(hb));
                }
            }
            cmk[t >> 6][t & 63] = cmb[(t >> 6)*2048 + kbase + (t & 63)];
        }
        __syncthreads();

        float ckv[4][4];
#pragma unroll
        for (int c = 0; c < 4; c++)
#pragma unroll
            for (int s = 0; s < 4; s++) ckv[c][s] = cmk[c][s*16 + col];

        // ---- S = Q.K^T  (3-term hi/lo split) ----
        f4v S[2][4];
#pragma unroll
        for (int m = 0; m < 2; m++)
#pragma unroll
        for (int s = 0; s < 4; s++) { f4v z = {0.f,0.f,0.f,0.f}; S[m][s] = z; }
#pragma unroll
        for (int s = 0; s < 4; s++)
#pragma unroll
        for (int c = 0; c < 2; c++) {
            const int off = (s*16 + col)*72 + c*32 + quad*8;
            s8v kh = *(const s8v*)&Ksh_h[off];
            s8v kl = *(const s8v*)&Ksh_l[off];
#pragma unroll
            for (int m = 0; m < 2; m++) {
                S[m][s] = mfma16(qh[m][c], kh, S[m][s]);
                S[m][s] = mfma16(qh[m][c], kl, S[m][s]);
                S[m][s] = mfma16(ql[m][c], kh, S[m][s]);
            }
        }

        // ---- bias + online softmax (log2 domain), write P hi/lo to LDS ----
#pragma unroll
        for (int m = 0; m < 2; m++) {
            const float* ip = imb + (size_t)(m*16 + quad*4)*2048 + kbase;
            float sr[4][4];
#pragma unroll
            for (int s = 0; s < 4; s++)
#pragma unroll
            for (int reg = 0; reg < 4; reg++) {
                float same = cq[0][m][reg]*ckv[0][s] + cq[1][m][reg]*ckv[1][s]
                           + cq[2][m][reg]*ckv[2][s] + cq[3][m][reg]*ckv[3][s];
                float imv = ip[(size_t)reg*2048 + s*16];
                sr[s][reg] = S[m][s][reg]*cS + same*aco[m][reg] + imv*cIm + cC;
            }
            float alpha[4];
#pragma unroll
            for (int reg = 0; reg < 4; reg++) {
                float rm = fmaxf(fmaxf(sr[0][reg], sr[1][reg]),
                                 fmaxf(sr[2][reg], sr[3][reg]));
                rm = fmaxf(rm, __shfl_xor(rm, 1));
                rm = fmaxf(rm, __shfl_xor(rm, 2));
                rm = fmaxf(rm, __shfl_xor(rm, 4));
                rm = fmaxf(rm, __shfl_xor(rm, 8));
                const float mn = fmaxf(mi[m][reg], rm);
                alpha[reg] = exp2f(mi[m][reg] - mn);
                mi[m][reg] = mn;
            }
            float rsum[4] = {0.f,0.f,0.f,0.f};
#pragma unroll
            for (int s = 0; s < 4; s++)
#pragma unroll
            for (int reg = 0; reg < 4; reg++) {
                float p = exp2f(sr[s][reg] - mi[m][reg]);
                sr[s][reg] = p;
                rsum[reg] += p;
            }
#pragma unroll
            for (int reg = 0; reg < 4; reg++) {
                float rsm = rsum[reg];
                rsm += __shfl_xor(rsm, 1);
                rsm += __shfl_xor(rsm, 2);
                rsm += __shfl_xor(rsm, 4);
                rsm += __shfl_xor(rsm, 8);
                li[m][reg] = li[m][reg]*alpha[reg] + rsm;
            }
#pragma unroll
            for (int n = 0; n < 4; n++)
#pragma unroll
                for (int reg = 0; reg < 4; reg++) Oa[m][n][reg] *= alpha[reg];
            const int rbase = w*32 + m*16 + quad*4;
#pragma unroll
            for (int s = 0; s < 4; s++)
#pragma unroll
            for (int reg = 0; reg < 4; reg++) {
                float p = sr[s][reg];
                unsigned short ph = f2bf(p);
                Ps_h[(rbase+reg)*72 + s*16 + col] = (short)ph;
                Ps_l[(rbase+reg)*72 + s*16 + col] = (short)f2bf(p - bf2f(ph));
            }
        }

        // ---- O += P.V  (3-term hi/lo split); P read back in A-layout ----
        s8v pa[2][2], pb[2][2];
#pragma unroll
        for (int m = 0; m < 2; m++)
#pragma unroll
        for (int kc = 0; kc < 2; kc++) {
            const int off = (w*32 + m*16 + col)*72 + kc*32 + quad*8;
            pa[m][kc] = *(const s8v*)&Ps_h[off];
            pb[m][kc] = *(const s8v*)&Ps_l[off];
        }
#pragma unroll
        for (int n = 0; n < 4; n++)
#pragma unroll
        for (int kc = 0; kc < 2; kc++) {
            const int off = (n*16 + col)*72 + kc*32 + quad*8;
            s8v vh = *(const s8v*)&Vt_h[off];
            s8v vl = *(const s8v*)&Vt_l[off];
#pragma unroll
            for (int m = 0; m < 2; m++) {
                Oa[m][n] = mfma16(pa[m][kc], vh, Oa[m][n]);
                Oa[m][n] = mfma16(pa[m][kc], vl, Oa[m][n]);
                Oa[m][n] = mfma16(pb[m][kc], vh, Oa[m][n]);
            }
        }
    }

    // ---- epilogue: O/li -> (B,N,D) ----
#pragma unroll
    for (int m = 0; m < 2; m++)
#pragma unroll
    for (int reg = 0; reg < 4; reg++) {
        const float inv = 1.0f / li[m][reg];
        const size_t row = (size_t)b*2048 + qbase + m*16 + quad*4 + reg;
#pragma unroll
        for (int n = 0; n < 4; n++)
            O[row*1024 + h*64 + n*16 + col] = Oa[m][n][reg] * inv;
    }
}

// ---------------------------------------------------------------------------
extern "C" void kernel_launch(void* const* d_in, const int* in_sizes, int n_in,
                              void* d_out, int out_size, void* d_ws, size_t ws_size,
                              hipStream_t stream)
{
    const float* x    = (const float*)d_in[0];
    const float* cm   = (const float*)d_in[1];
    const float* im   = (const float*)d_in[2];
    const float* Wqkv = (const float*)d_in[3];
    const float* Wout = (const float*)d_in[4];
    const float* qw   = (const float*)d_in[5];
    const float* kw   = (const float*)d_in[6];
    const float* gate = (const float*)d_in[7];
    float* out = (float*)d_out;

    float* ws = (float*)d_ws;
    float* qb = ws;                   // (B,H,N,HD)
    float* kb = qb + 4194304;
    float* vb = kb + 4194304;
    float* ob = vb + 4194304;         // (B,N,D)
    float* rsbuf = ob + 4194304;      // (B,N)

    gemm_nt<0><<<dim3(24, 32), 256, 0, stream>>>(x, Wqkv, qb, kb, vb);
    rmsnorm_k<<<16384, 256, 0, stream>>>(qb, qw);
    rmsnorm_k<<<16384, 256, 0, stream>>>(kb, kw);
    rowscale_k<<<64, 256, 0, stream>>>(cm, rsbuf);
    attn_mfma<<<512, 256, 0, stream>>>(qb, kb, vb, cm, im, rsbuf, gate, ob);
    gemm_nt<1><<<dim3(8, 32), 256, 0, stream>>>(ob, Wout, out, nullptr, nullptr);
}

// Round 3
// 792.538 us; speedup vs baseline: 1.4815x; 1.3155x over previous
//
#include <hip/hip_runtime.h>
#include <math.h>

// Problem constants: B=2, N=2048, D=1024, H=16, HD=64, C=4
// ws (floats): q[4194304] k[4194304] v[4194304] o[4194304] rs[4096] bias2[8388608]

typedef __attribute__((ext_vector_type(8))) short s8v;
typedef __attribute__((ext_vector_type(4))) short s4v;
typedef __attribute__((ext_vector_type(4))) float f4v;

#define L2E 1.44269504088896340736f

__device__ __forceinline__ unsigned short f2bf(float x) {
    union { float f; unsigned u; } v; v.f = x;
    unsigned r = v.u + 0x7FFF + ((v.u >> 16) & 1);
    return (unsigned short)(r >> 16);
}
__device__ __forceinline__ float bf2f(unsigned short h) {
    union { unsigned u; float f; } v; v.u = ((unsigned)h) << 16;
    return v.f;
}
__device__ __forceinline__ f4v mfma32(s8v a, s8v b, f4v c) {
    return __builtin_amdgcn_mfma_f32_16x16x32_bf16(a, b, c, 0, 0, 0);
}
__device__ __forceinline__ f4v mfma16x16(s4v a, s4v b, f4v c) {
    return __builtin_amdgcn_mfma_f32_16x16x16bf16_1k(a, b, c, 0, 0, 0);
}

// ---------------------------------------------------------------------------
// GEMM  C[M,x] = A[M,1024] * B[x,1024]^T  (fp32 vector; unchanged, passing)
// ---------------------------------------------------------------------------
template<int MODE>
__global__ __launch_bounds__(256)
void gemm_nt(const float* __restrict__ A, const float* __restrict__ Bm,
             float* __restrict__ C0, float* __restrict__ C1, float* __restrict__ C2)
{
    __shared__ __align__(16) float As[16][132];
    __shared__ __align__(16) float Bs[16][132];
    const int t    = threadIdx.x;
    const int m0   = blockIdx.y * 128;
    const int n0   = blockIdx.x * 128;
    const int trow = t >> 4;
    const int tcol = t & 15;

    float acc[8][8];
#pragma unroll
    for (int i = 0; i < 8; i++)
#pragma unroll
        for (int j = 0; j < 8; j++) acc[i][j] = 0.f;

    const int lr = t >> 2;
    const int lc = (t & 3) * 4;
    const float* ap0 = A  + (size_t)(m0 + lr) * 1024 + lc;
    const float* ap1 = A  + (size_t)(m0 + 64 + lr) * 1024 + lc;
    const float* bp0 = Bm + (size_t)(n0 + lr) * 1024 + lc;
    const float* bp1 = Bm + (size_t)(n0 + 64 + lr) * 1024 + lc;

    for (int k0 = 0; k0 < 1024; k0 += 16) {
        float4 a0 = *(const float4*)(ap0 + k0);
        float4 a1 = *(const float4*)(ap1 + k0);
        float4 b0 = *(const float4*)(bp0 + k0);
        float4 b1 = *(const float4*)(bp1 + k0);
        __syncthreads();
        As[lc+0][lr]    = a0.x; As[lc+1][lr]    = a0.y; As[lc+2][lr]    = a0.z; As[lc+3][lr]    = a0.w;
        As[lc+0][64+lr] = a1.x; As[lc+1][64+lr] = a1.y; As[lc+2][64+lr] = a1.z; As[lc+3][64+lr] = a1.w;
        Bs[lc+0][lr]    = b0.x; Bs[lc+1][lr]    = b0.y; Bs[lc+2][lr]    = b0.z; Bs[lc+3][lr]    = b0.w;
        Bs[lc+0][64+lr] = b1.x; Bs[lc+1][64+lr] = b1.y; Bs[lc+2][64+lr] = b1.z; Bs[lc+3][64+lr] = b1.w;
        __syncthreads();
#pragma unroll
        for (int kk = 0; kk < 16; kk++) {
            float4 alo = *(const float4*)&As[kk][trow*4];
            float4 ahi = *(const float4*)&As[kk][64+trow*4];
            float4 blo = *(const float4*)&Bs[kk][tcol*4];
            float4 bhi = *(const float4*)&Bs[kk][64+tcol*4];
            float a[8]  = {alo.x,alo.y,alo.z,alo.w, ahi.x,ahi.y,ahi.z,ahi.w};
            float bb[8] = {blo.x,blo.y,blo.z,blo.w, bhi.x,bhi.y,bhi.z,bhi.w};
#pragma unroll
            for (int i = 0; i < 8; i++)
#pragma unroll
                for (int j = 0; j < 8; j++)
                    acc[i][j] = fmaf(a[i], bb[j], acc[i][j]);
        }
    }

#pragma unroll
    for (int ih = 0; ih < 2; ih++)
#pragma unroll
    for (int i = 0; i < 4; i++) {
        const int m = m0 + ih*64 + trow*4 + i;
#pragma unroll
        for (int jh = 0; jh < 2; jh++) {
            const int col = n0 + jh*64 + tcol*4;
            float4 v = make_float4(acc[ih*4+i][jh*4+0], acc[ih*4+i][jh*4+1],
                                   acc[ih*4+i][jh*4+2], acc[ih*4+i][jh*4+3]);
            if (MODE == 0) {
                const int b = m >> 11, n = m & 2047;
                const int which = col >> 10, rem = col & 1023;
                const int h = rem >> 6, hd = rem & 63;
                float* dst = (which == 0 ? C0 : (which == 1 ? C1 : C2));
                *(float4*)(dst + ((((size_t)b*16 + h)*2048 + n)*64 + hd)) = v;
            } else {
                *(float4*)(C0 + (size_t)m * 1024 + col) = v;
            }
        }
    }
}

// ---------------------------------------------------------------------------
// RMSNorm over last dim 64, in place.
// ---------------------------------------------------------------------------
__global__ __launch_bounds__(256)
void rmsnorm_k(float* __restrict__ t, const float* __restrict__ w)
{
    const int row  = blockIdx.x * 4 + (threadIdx.x >> 6);
    const int lane = threadIdx.x & 63;
    const size_t idx = (size_t)row * 64 + lane;
    float v = t[idx];
    float s = v * v;
#pragma unroll
    for (int off = 32; off; off >>= 1) s += __shfl_xor(s, off);
    float sc = rsqrtf(s * (1.0f/64.0f) + 1e-6f);
    t[idx] = v * sc * w[lane];
}

// ---------------------------------------------------------------------------
// rowscale[b,q] = 1 / max(max_k dot4(cm[b,:,q], cm[b,:,k]), 1e-6)
// ---------------------------------------------------------------------------
__global__ __launch_bounds__(256)
void rowscale_k(const float* __restrict__ cm, float* __restrict__ rs)
{
    __shared__ float cms[4][2048];
    const int b  = blockIdx.x >> 5;
    const int qt = blockIdx.x & 31;
    const float* base = cm + (size_t)b * 4 * 2048;
    for (int i = threadIdx.x; i < 2048; i += 256) {
        cms[0][i] = base[i];
        cms[1][i] = base[2048 + i];
        cms[2][i] = base[4096 + i];
        cms[3][i] = base[6144 + i];
    }
    __syncthreads();
    const int q    = qt * 64 + (threadIdx.x >> 2);
    const int part = threadIdx.x & 3;
    const float a0 = cms[0][q], a1 = cms[1][q], a2 = cms[2][q], a3 = cms[3][q];
    float mx = 0.f;
    for (int i = 0; i < 512; i++) {
        const int k = part + 4 * i;
        float d = a0*cms[0][k] + a1*cms[1][k] + a2*cms[2][k] + a3*cms[3][k];
        mx = fmaxf(mx, d);
    }
    mx = fmaxf(mx, __shfl_xor(mx, 1));
    mx = fmaxf(mx, __shfl_xor(mx, 2));
    if (part == 0) rs[b * 2048 + q] = 1.0f / fmaxf(mx, 1e-6f);
}

// ---------------------------------------------------------------------------
// Bias precompute:  Bias2[b][k>>2][q][k&3] = (dot4(cm_q,cm_k)*rsq - 0.5)*2
//                                            + 0.3*im[b][q][k]
// k-major tiled layout -> attention reads one coalesced float4 per (s,n).
// grid 256 = b(2) x kt(32) x qq(4); 256 threads; 32 iters of 16 q-rows.
// ---------------------------------------------------------------------------
__global__ __launch_bounds__(256)
void bias_pre(const float* __restrict__ cm, const float* __restrict__ im,
              const float* __restrict__ rs, float* __restrict__ Bias2)
{
    const int bid = blockIdx.x;
    const int qq = bid & 3;
    const int kt = (bid >> 2) & 31;
    const int b  = bid >> 7;

    __shared__ float cmk[4][64];
    const int t = threadIdx.x;
    const int k0 = kt * 64;
    cmk[t >> 6][t & 63] = cm[(size_t)b*8192 + (t >> 6)*2048 + k0 + (t & 63)];
    __syncthreads();

    const int klane = t & 15;
    const int qrow  = t >> 4;
    const int kk = k0 + klane*4;
    const int kg = kk >> 2;
    float ck[4][4];
#pragma unroll
    for (int c = 0; c < 4; c++)
#pragma unroll
        for (int j = 0; j < 4; j++) ck[c][j] = cmk[c][klane*4 + j];

    const float* cmb = cm + (size_t)b * 8192;
    for (int it = 0; it < 32; it++) {
        const int q = qq*512 + it*16 + qrow;
        float4 imv = *(const float4*)(im + ((size_t)b*2048 + q)*2048 + kk);
        const float rsq = rs[b*2048 + q];
        const float c0 = cmb[q], c1 = cmb[2048+q], c2 = cmb[4096+q], c3 = cmb[6144+q];
        float o[4];
        float iv[4] = {imv.x, imv.y, imv.z, imv.w};
#pragma unroll
        for (int j = 0; j < 4; j++) {
            float same = c0*ck[0][j] + c1*ck[1][j] + c2*ck[2][j] + c3*ck[3][j];
            o[j] = (same*rsq - 0.5f)*2.0f + 0.3f*iv[j];
        }
        *(float4*)(Bias2 + (((size_t)b*512 + kg)*2048 + q)*4) =
            make_float4(o[0], o[1], o[2], o[3]);
    }
}

// ---------------------------------------------------------------------------
// Flash attention, S^T orientation.
//   S^T = K·Q^T via mfma_f32_16x16x32_bf16 (hi/lo 3-term): C row = key, col = q.
//   P^T (= S^T C-regs after softmax) feeds PV DIRECTLY as the B operand of
//   mfma_f32_16x16x16_bf16 (1k): B[k=quad*4+j][n=col] == C-layout. No LDS
//   round-trip for P, no shfl transform.
//   O^T = V^T·P^T: A = V^T from u32-packed (hi|lo<<16) transposed LDS tile.
// Block = (b,h,128-q tile), 4 waves x 32 q (2 n-tiles of 16). 64-key k-tiles.
// LDS = 35.8 KB (K hi/lo planes [64][72] + Vt u32 [64][68]).
// ---------------------------------------------------------------------------
#define KPAD 72   // shorts per K-plane row
#define VPAD 68   // u32 per Vt row (even -> 16B-aligned b128 reads)

__global__ __launch_bounds__(256, 2)
void attn_mfma(const float* __restrict__ Q, const float* __restrict__ K,
               const float* __restrict__ V, const float* __restrict__ Bias2,
               const float* __restrict__ gate, float* __restrict__ O)
{
    const int bid = blockIdx.x;
    const int h  = bid & 15;            // h fastest: heads share Bias2 in L2
    const int qt = (bid >> 4) & 15;
    const int b  = bid >> 8;

    __shared__ __align__(16) short    Kh[64*KPAD];
    __shared__ __align__(16) short    Kl[64*KPAD];
    __shared__ __align__(16) unsigned Vt[64*VPAD];   // [d][key], hi | lo<<16

    const int t    = threadIdx.x;
    const int w    = t >> 6;
    const int lane = t & 63;
    const int col  = lane & 15;
    const int quad = lane >> 4;

    const size_t headoff = ((size_t)(b*16 + h)) * 2048 * 64;
    const float* Qh = Q + headoff;
    const float* Kg = K + headoff;
    const float* Vg = V + headoff;

    const int qb = qt*128 + w*32;       // this wave's 32 q rows

    // ---- Q B-fragments (hi/lo) in registers: B[d=quad*8+j][q=col] ----
    s8v qfh[2][2], qfl[2][2];           // [n][c]
#pragma unroll
    for (int n = 0; n < 2; n++)
#pragma unroll
    for (int c = 0; c < 2; c++) {
        const float* p = Qh + (size_t)(qb + n*16 + col)*64 + c*32 + quad*8;
        float4 f0 = *(const float4*)(p);
        float4 f1 = *(const float4*)(p + 4);
        float fv[8] = {f0.x,f0.y,f0.z,f0.w, f1.x,f1.y,f1.z,f1.w};
        s8v hi, lo;
#pragma unroll
        for (int j = 0; j < 8; j++) {
            unsigned short hb = f2bf(fv[j]);
            hi[j] = (short)hb;
            lo[j] = (short)f2bf(fv[j] - bf2f(hb));
        }
        qfh[n][c] = hi; qfl[n][c] = lo;
    }

    const float g  = fminf(fmaxf(gate[h], 0.f), 1.f);
    const float cS = 0.125f * L2E;
    const float cB = 3.0f * g * L2E;

    float mi[2] = {-INFINITY, -INFINITY};
    float li[2] = {0.f, 0.f};
    f4v Oa[4][2];                       // O^T frags: [dt][n]
#pragma unroll
    for (int dt = 0; dt < 4; dt++)
#pragma unroll
        for (int n = 0; n < 2; n++) { f4v z = {0.f,0.f,0.f,0.f}; Oa[dt][n] = z; }

    const int skey = t >> 2;            // staging: key row 0..63
    const int sc   = t & 3;             // d-chunk selector

    for (int kt2 = 0; kt2 < 32; kt2++) {
        const int kbase = kt2 * 64;

        // ---- bias prefetch (coalesced float4; in flight during staging) ----
        float4 bias[4][2];
#pragma unroll
        for (int s = 0; s < 4; s++)
#pragma unroll
        for (int n = 0; n < 2; n++) {
            const int kg = (kbase >> 2) + s*4 + quad;
            bias[s][n] = *(const float4*)(Bias2 +
                (((size_t)b*512 + kg)*2048 + qb + n*16 + col)*4);
        }

        __syncthreads();                // everyone done reading previous K/V
        // ---- stage K hi/lo planes + V^T u32-packed ----
#pragma unroll
        for (int i = 0; i < 4; i++) {
            const int d0 = sc*4 + i*16;
            float4 kf = *(const float4*)(Kg + (size_t)(kbase + skey)*64 + d0);
            float ka[4] = {kf.x, kf.y, kf.z, kf.w};
            s4v kh4, kl4;
#pragma unroll
            for (int j = 0; j < 4; j++) {
                unsigned short hb = f2bf(ka[j]);
                kh4[j] = (short)hb;
                kl4[j] = (short)f2bf(ka[j] - bf2f(hb));
            }
            *(s4v*)&Kh[skey*KPAD + d0] = kh4;
            *(s4v*)&Kl[skey*KPAD + d0] = kl4;

            float4 vf = *(const float4*)(Vg + (size_t)(kbase + skey)*64 + d0);
            float va[4] = {vf.x, vf.y, vf.z, vf.w};
#pragma unroll
            for (int j = 0; j < 4; j++) {
                unsigned short hb = f2bf(va[j]);
                unsigned short lb = f2bf(va[j] - bf2f(hb));
                Vt[(d0 + j)*VPAD + skey] = (unsigned)hb | ((unsigned)lb << 16);
            }
        }
        __syncthreads();

        // ---- S^T = K·Q^T (3-term hi/lo) ----
        f4v S[4][2];
#pragma unroll
        for (int s = 0; s < 4; s++)
#pragma unroll
            for (int n = 0; n < 2; n++) { f4v z = {0.f,0.f,0.f,0.f}; S[s][n] = z; }
#pragma unroll
        for (int s = 0; s < 4; s++)
#pragma unroll
        for (int c = 0; c < 2; c++) {
            const int off = (s*16 + col)*KPAD + c*32 + quad*8;
            s8v kh = *(const s8v*)&Kh[off];
            s8v kl = *(const s8v*)&Kl[off];
#pragma unroll
            for (int n = 0; n < 2; n++) {
                S[s][n] = mfma32(kh, qfh[n][c], S[s][n]);
                S[s][n] = mfma32(kh, qfl[n][c], S[s][n]);
                S[s][n] = mfma32(kl, qfh[n][c], S[s][n]);
            }
        }

        // ---- bias + online softmax (log2 domain); P^T stays in registers ----
        s4v ph[4][2], pl[4][2];
        float alpha[2];
#pragma unroll
        for (int n = 0; n < 2; n++) {
            float sr[4][4];
            float rmax = -INFINITY;
#pragma unroll
            for (int s = 0; s < 4; s++) {
                float bv[4] = {bias[s][n].x, bias[s][n].y, bias[s][n].z, bias[s][n].w};
#pragma unroll
                for (int r = 0; r < 4; r++) {
                    sr[s][r] = S[s][n][r]*cS + bv[r]*cB;
                    rmax = fmaxf(rmax, sr[s][r]);
                }
            }
            rmax = fmaxf(rmax, __shfl_xor(rmax, 16));
            rmax = fmaxf(rmax, __shfl_xor(rmax, 32));
            const float mnew = fmaxf(mi[n], rmax);
            alpha[n] = exp2f(mi[n] - mnew);
            float rsum = 0.f;
#pragma unroll
            for (int s = 0; s < 4; s++) {
                s4v hh, ll;
#pragma unroll
                for (int r = 0; r < 4; r++) {
                    float pv = exp2f(sr[s][r] - mnew);
                    rsum += pv;
                    union { float f; unsigned u; } uu; uu.f = pv;
                    unsigned short hb = (unsigned short)(uu.u >> 16);  // trunc split
                    hh[r] = (short)hb;
                    ll[r] = (short)f2bf(pv - bf2f(hb));
                }
                ph[s][n] = hh; pl[s][n] = ll;
            }
            rsum += __shfl_xor(rsum, 16);
            rsum += __shfl_xor(rsum, 32);
            li[n] = li[n]*alpha[n] + rsum;
            mi[n] = mnew;
        }

        // ---- rescale O, then O^T += V^T·P^T (3-term) ----
#pragma unroll
        for (int dt = 0; dt < 4; dt++)
#pragma unroll
        for (int n = 0; n < 2; n++)
#pragma unroll
            for (int r = 0; r < 4; r++) Oa[dt][n][r] *= alpha[n];

#pragma unroll
        for (int dt = 0; dt < 4; dt++)
#pragma unroll
        for (int s = 0; s < 4; s++) {
            uint4 u = *(const uint4*)&Vt[(dt*16 + col)*VPAD + s*16 + quad*4];
            unsigned ua[4] = {u.x, u.y, u.z, u.w};
            s4v vh, vl;
#pragma unroll
            for (int j = 0; j < 4; j++) {
                vh[j] = (short)(ua[j] & 0xffffu);
                vl[j] = (short)(ua[j] >> 16);
            }
#pragma unroll
            for (int n = 0; n < 2; n++) {
                Oa[dt][n] = mfma16x16(vh, ph[s][n], Oa[dt][n]);
                Oa[dt][n] = mfma16x16(vl, ph[s][n], Oa[dt][n]);
                Oa[dt][n] = mfma16x16(vh, pl[s][n], Oa[dt][n]);
            }
        }
    }

    // ---- epilogue: O^T -> (B,N,D), coalesced float4 along d ----
#pragma unroll
    for (int n = 0; n < 2; n++) {
        const float inv = 1.0f / li[n];
        const size_t row = (size_t)b*2048 + qb + n*16 + col;
#pragma unroll
        for (int dt = 0; dt < 4; dt++) {
            float4 ov = make_float4(Oa[dt][n][0]*inv, Oa[dt][n][1]*inv,
                                    Oa[dt][n][2]*inv, Oa[dt][n][3]*inv);
            *(float4*)(O + row*1024 + h*64 + dt*16 + quad*4) = ov;
        }
    }
}

// ---------------------------------------------------------------------------
extern "C" void kernel_launch(void* const* d_in, const int* in_sizes, int n_in,
                              void* d_out, int out_size, void* d_ws, size_t ws_size,
                              hipStream_t stream)
{
    const float* x    = (const float*)d_in[0];
    const float* cm   = (const float*)d_in[1];
    const float* im   = (const float*)d_in[2];
    const float* Wqkv = (const float*)d_in[3];
    const float* Wout = (const float*)d_in[4];
    const float* qw   = (const float*)d_in[5];
    const float* kw   = (const float*)d_in[6];
    const float* gate = (const float*)d_in[7];
    float* out = (float*)d_out;

    float* ws = (float*)d_ws;
    float* qb = ws;                   // (B,H,N,HD)
    float* kb = qb + 4194304;
    float* vb = kb + 4194304;
    float* ob = vb + 4194304;         // (B,N,D)
    float* rsbuf = ob + 4194304;      // (B,N)
    float* bias2 = rsbuf + 4096;      // (B, N/4, N, 4)

    gemm_nt<0><<<dim3(24, 32), 256, 0, stream>>>(x, Wqkv, qb, kb, vb);
    rmsnorm_k<<<16384, 256, 0, stream>>>(qb, qw);
    rmsnorm_k<<<16384, 256, 0, stream>>>(kb, kw);
    rowscale_k<<<64, 256, 0, stream>>>(cm, rsbuf);
    bias_pre<<<256, 256, 0, stream>>>(cm, im, rsbuf, bias2);
    attn_mfma<<<512, 256, 0, stream>>>(qb, kb, vb, bias2, gate, ob);
    gemm_nt<1><<<dim3(8, 32), 256, 0, stream>>>(ob, Wout, out, nullptr, nullptr);
}

// Round 4
// 477.607 us; speedup vs baseline: 2.4584x; 1.6594x over previous
//
#include <hip/hip_runtime.h>
#include <math.h>

// Problem constants: B=2, N=2048, D=1024, H=16, HD=64, C=4

typedef __attribute__((ext_vector_type(8))) short s8v;
typedef __attribute__((ext_vector_type(4))) short s4v;
typedef __attribute__((ext_vector_type(4))) float f4v;

#define L2E 1.44269504088896340736f

__device__ __forceinline__ unsigned short f2bf(float x) {
    union { float f; unsigned u; } v; v.f = x;
    unsigned r = v.u + 0x7FFF + ((v.u >> 16) & 1);
    return (unsigned short)(r >> 16);
}
__device__ __forceinline__ float bf2f(unsigned short h) {
    union { unsigned u; float f; } v; v.u = ((unsigned)h) << 16;
    return v.f;
}
__device__ __forceinline__ f4v mfma32(s8v a, s8v b, f4v c) {
    return __builtin_amdgcn_mfma_f32_16x16x32_bf16(a, b, c, 0, 0, 0);
}
__device__ __forceinline__ f4v mfma16x16(s4v a, s4v b, f4v c) {
    return __builtin_amdgcn_mfma_f32_16x16x16bf16_1k(a, b, c, 0, 0, 0);
}
__device__ __forceinline__ void gl_lds16(const void* g, void* l) {
    __builtin_amdgcn_global_load_lds(
        (const __attribute__((address_space(1))) unsigned*)g,
        (__attribute__((address_space(3))) unsigned*)l, 16, 0, 0);
}

// ---------------------------------------------------------------------------
// Split fp32 tensor into bf16 hi/lo planes.  n4 = elem_count/4.
// ---------------------------------------------------------------------------
__global__ __launch_bounds__(256)
void planes_k(const float* __restrict__ src, short* __restrict__ ph,
              short* __restrict__ pl)
{
    const int i = blockIdx.x * 256 + threadIdx.x;
    float4 f = ((const float4*)src)[i];
    float fa[4] = {f.x, f.y, f.z, f.w};
    s4v h4, l4;
#pragma unroll
    for (int j = 0; j < 4; j++) {
        unsigned short hb = f2bf(fa[j]);
        h4[j] = (short)hb;
        l4[j] = (short)f2bf(fa[j] - bf2f(hb));
    }
    ((s4v*)ph)[i] = h4;
    ((s4v*)pl)[i] = l4;
}

// ---------------------------------------------------------------------------
// MFMA GEMM  C[M,NC] = A[M,1024] * B[NC,1024]^T  from bf16 hi/lo planes.
// 3-term split: Ah*Bh + Ah*Bl + Al*Bh.  128x128 tile, BK=64, 16 iters.
// Staging via global_load_lds width=16 into unpadded LDS with XOR(row&7)
// source-side swizzle (conflict-free frag ds_read_b128).
// MODE 0: scatter epilogue -> packed u32 (hi|lo<<16) q/k/v in (B,H,N,HD).
// MODE 1: plain fp32 row-major Cout.
// ---------------------------------------------------------------------------
template<int MODE>
__global__ __launch_bounds__(256, 2)
void gemm_mfma(const short* __restrict__ Ah, const short* __restrict__ Al,
               const short* __restrict__ Bh, const short* __restrict__ Bl,
               unsigned* __restrict__ Pq, unsigned* __restrict__ Pk,
               unsigned* __restrict__ Pv, float* __restrict__ Cout)
{
    __shared__ short sAh[128*64], sAl[128*64], sBh[128*64], sBl[128*64];

    const int t    = threadIdx.x;
    const int w    = t >> 6;
    const int lane = t & 63;
    const int wm   = w >> 1, wn = w & 1;
    const int col  = lane & 15, quad = lane >> 4;
    const int m0   = blockIdx.y * 128;
    const int n0   = blockIdx.x * 128;

    f4v acc[4][4];
#pragma unroll
    for (int i = 0; i < 4; i++)
#pragma unroll
        for (int j = 0; j < 4; j++) { f4v z = {0.f,0.f,0.f,0.f}; acc[i][j] = z; }

    // staging source: row = w*32 + j*8 + (lane>>3); swizzled chunk (shorts)
    const int srow   = w*32 + (lane >> 3);
    const int schunk = ((lane & 7) ^ (lane >> 3)) * 8;
    const short* agh = Ah + (size_t)(m0 + srow)*1024 + schunk;
    const short* agl = Al + (size_t)(m0 + srow)*1024 + schunk;
    const short* bgh = Bh + (size_t)(n0 + srow)*1024 + schunk;
    const short* bgl = Bl + (size_t)(n0 + srow)*1024 + schunk;
    const int sbase = (w*32) * 64;

    for (int kt = 0; kt < 16; kt++) {
        const int k0 = kt * 64;
        __syncthreads();
#pragma unroll
        for (int j = 0; j < 4; j++) {
            gl_lds16(agh + k0 + j*8*1024, &sAh[sbase + j*8*64]);
            gl_lds16(agl + k0 + j*8*1024, &sAl[sbase + j*8*64]);
            gl_lds16(bgh + k0 + j*8*1024, &sBh[sbase + j*8*64]);
            gl_lds16(bgl + k0 + j*8*1024, &sBl[sbase + j*8*64]);
        }
        __syncthreads();
#pragma unroll
        for (int kc = 0; kc < 2; kc++) {
            s8v ahf[4], alf[4], bhf[4], blf[4];
            const int sw = ((kc*4 + quad) ^ (col & 7)) * 8;
#pragma unroll
            for (int i = 0; i < 4; i++) {
                const int aoff = (wm*64 + i*16 + col)*64 + sw;
                ahf[i] = *(const s8v*)&sAh[aoff];
                alf[i] = *(const s8v*)&sAl[aoff];
                const int boff = (wn*64 + i*16 + col)*64 + sw;
                bhf[i] = *(const s8v*)&sBh[boff];
                blf[i] = *(const s8v*)&sBl[boff];
            }
#pragma unroll
            for (int i = 0; i < 4; i++)
#pragma unroll
            for (int j = 0; j < 4; j++) {
                acc[i][j] = mfma32(ahf[i], bhf[j], acc[i][j]);
                acc[i][j] = mfma32(ahf[i], blf[j], acc[i][j]);
                acc[i][j] = mfma32(alf[i], bhf[j], acc[i][j]);
            }
        }
    }

#pragma unroll
    for (int i = 0; i < 4; i++)
#pragma unroll
    for (int j = 0; j < 4; j++) {
        const int gcol = n0 + wn*64 + j*16 + col;
#pragma unroll
        for (int r = 0; r < 4; r++) {
            const int grow = m0 + wm*64 + i*16 + quad*4 + r;
            const float v = acc[i][j][r];
            if (MODE == 0) {
                const int which = gcol >> 10;
                const int hh = (gcol >> 6) & 15;
                const int hd = gcol & 63;
                const int b = grow >> 11, nn = grow & 2047;
                unsigned* dst = which == 0 ? Pq : (which == 1 ? Pk : Pv);
                unsigned short hb = f2bf(v);
                unsigned short lb = f2bf(v - bf2f(hb));
                dst[((size_t)(b*16 + hh)*2048 + nn)*64 + hd] =
                    (unsigned)hb | ((unsigned)lb << 16);
            } else {
                Cout[(size_t)grow*1024 + gcol] = v;
            }
        }
    }
}

// ---------------------------------------------------------------------------
// RMSNorm over last dim 64, in place on packed u32 (hi|lo<<16) planes.
// ---------------------------------------------------------------------------
__global__ __launch_bounds__(256)
void rmsnorm_p(unsigned* __restrict__ t, const float* __restrict__ w)
{
    const int row  = blockIdx.x * 4 + (threadIdx.x >> 6);
    const int lane = threadIdx.x & 63;
    const size_t idx = (size_t)row * 64 + lane;
    const unsigned u = t[idx];
    float v = bf2f((unsigned short)(u & 0xffffu)) + bf2f((unsigned short)(u >> 16));
    float s = v * v;
#pragma unroll
    for (int off = 32; off; off >>= 1) s += __shfl_xor(s, off);
    float sc = rsqrtf(s * (1.0f/64.0f) + 1e-6f);
    float y = v * sc * w[lane];
    unsigned short hb = f2bf(y);
    t[idx] = (unsigned)hb | ((unsigned)f2bf(y - bf2f(hb)) << 16);
}

// ---------------------------------------------------------------------------
// rowscale[b,q] = 1 / max(max_k dot4(cm[b,:,q], cm[b,:,k]), 1e-6)
// ---------------------------------------------------------------------------
__global__ __launch_bounds__(256)
void rowscale_k(const float* __restrict__ cm, float* __restrict__ rs)
{
    __shared__ float cms[4][2048];
    const int b  = blockIdx.x >> 5;
    const int qt = blockIdx.x & 31;
    const float* base = cm + (size_t)b * 4 * 2048;
    for (int i = threadIdx.x; i < 2048; i += 256) {
        cms[0][i] = base[i];
        cms[1][i] = base[2048 + i];
        cms[2][i] = base[4096 + i];
        cms[3][i] = base[6144 + i];
    }
    __syncthreads();
    const int q    = qt * 64 + (threadIdx.x >> 2);
    const int part = threadIdx.x & 3;
    const float a0 = cms[0][q], a1 = cms[1][q], a2 = cms[2][q], a3 = cms[3][q];
    float mx = 0.f;
    for (int i = 0; i < 512; i++) {
        const int k = part + 4 * i;
        float d = a0*cms[0][k] + a1*cms[1][k] + a2*cms[2][k] + a3*cms[3][k];
        mx = fmaxf(mx, d);
    }
    mx = fmaxf(mx, __shfl_xor(mx, 1));
    mx = fmaxf(mx, __shfl_xor(mx, 2));
    if (part == 0) rs[b * 2048 + q] = 1.0f / fmaxf(mx, 1e-6f);
}

// ---------------------------------------------------------------------------
// Bias precompute:  Bias2[b][k>>2][q][k&3] = (dot4(cm_q,cm_k)*rsq - 0.5)*2
//                                            + 0.3*im[b][q][k]
// ---------------------------------------------------------------------------
__global__ __launch_bounds__(256)
void bias_pre(const float* __restrict__ cm, const float* __restrict__ im,
              const float* __restrict__ rs, float* __restrict__ Bias2)
{
    const int bid = blockIdx.x;
    const int qq = bid & 3;
    const int kt = (bid >> 2) & 31;
    const int b  = bid >> 7;

    __shared__ float cmk[4][64];
    const int t = threadIdx.x;
    const int k0 = kt * 64;
    cmk[t >> 6][t & 63] = cm[(size_t)b*8192 + (t >> 6)*2048 + k0 + (t & 63)];
    __syncthreads();

    const int klane = t & 15;
    const int qrow  = t >> 4;
    const int kk = k0 + klane*4;
    const int kg = kk >> 2;
    float ck[4][4];
#pragma unroll
    for (int c = 0; c < 4; c++)
#pragma unroll
        for (int j = 0; j < 4; j++) ck[c][j] = cmk[c][klane*4 + j];

    const float* cmb = cm + (size_t)b * 8192;
    for (int it = 0; it < 32; it++) {
        const int q = qq*512 + it*16 + qrow;
        float4 imv = *(const float4*)(im + ((size_t)b*2048 + q)*2048 + kk);
        const float rsq = rs[b*2048 + q];
        const float c0 = cmb[q], c1 = cmb[2048+q], c2 = cmb[4096+q], c3 = cmb[6144+q];
        float o[4];
        float iv[4] = {imv.x, imv.y, imv.z, imv.w};
#pragma unroll
        for (int j = 0; j < 4; j++) {
            float same = c0*ck[0][j] + c1*ck[1][j] + c2*ck[2][j] + c3*ck[3][j];
            o[j] = (same*rsq - 0.5f)*2.0f + 0.3f*iv[j];
        }
        *(float4*)(Bias2 + (((size_t)b*512 + kg)*2048 + q)*4) =
            make_float4(o[0], o[1], o[2], o[3]);
    }
}

// ---------------------------------------------------------------------------
// Flash attention, S^T orientation (round-3 structure), now reading packed
// u32 (hi|lo<<16) q/k/v planes (zero float->bf16 conversion in the loop) and
// writing bf16 hi/lo o-planes for the MFMA out-projection.
// ---------------------------------------------------------------------------
#define KPAD 72   // shorts per K-plane row
#define VPAD 68   // u32 per Vt row

__global__ __launch_bounds__(256, 2)
void attn_mfma(const unsigned* __restrict__ Qp, const unsigned* __restrict__ Kp,
               const unsigned* __restrict__ Vp, const float* __restrict__ Bias2,
               const float* __restrict__ gate, short* __restrict__ Oh,
               short* __restrict__ Ol)
{
    const int bid = blockIdx.x;
    const int h  = bid & 15;
    const int qt = (bid >> 4) & 15;
    const int b  = bid >> 8;

    __shared__ __align__(16) short    Kh[64*KPAD];
    __shared__ __align__(16) short    Kl[64*KPAD];
    __shared__ __align__(16) unsigned Vt[64*VPAD];   // [d][key], hi | lo<<16

    const int t    = threadIdx.x;
    const int w    = t >> 6;
    const int lane = t & 63;
    const int col  = lane & 15;
    const int quad = lane >> 4;

    const size_t headoff = ((size_t)(b*16 + h)) * 2048 * 64;
    const unsigned* Qh = Qp + headoff;
    const unsigned* Kg = Kp + headoff;
    const unsigned* Vg = Vp + headoff;

    const int qb = qt*128 + w*32;

    // ---- Q B-fragments (hi/lo) from packed planes ----
    s8v qfh[2][2], qfl[2][2];
#pragma unroll
    for (int n = 0; n < 2; n++)
#pragma unroll
    for (int c = 0; c < 2; c++) {
        const unsigned* p = Qh + (size_t)(qb + n*16 + col)*64 + c*32 + quad*8;
        uint4 u0 = *(const uint4*)p;
        uint4 u1 = *(const uint4*)(p + 4);
        unsigned ua[8] = {u0.x,u0.y,u0.z,u0.w, u1.x,u1.y,u1.z,u1.w};
        s8v hi, lo;
#pragma unroll
        for (int j = 0; j < 8; j++) {
            hi[j] = (short)(ua[j] & 0xffffu);
            lo[j] = (short)(ua[j] >> 16);
        }
        qfh[n][c] = hi; qfl[n][c] = lo;
    }

    const float g  = fminf(fmaxf(gate[h], 0.f), 1.f);
    const float cS = 0.125f * L2E;
    const float cB = 3.0f * g * L2E;

    float mi[2] = {-INFINITY, -INFINITY};
    float li[2] = {0.f, 0.f};
    f4v Oa[4][2];
#pragma unroll
    for (int dt = 0; dt < 4; dt++)
#pragma unroll
        for (int n = 0; n < 2; n++) { f4v z = {0.f,0.f,0.f,0.f}; Oa[dt][n] = z; }

    const int skey = t >> 2;
    const int sc   = t & 3;

    for (int kt2 = 0; kt2 < 32; kt2++) {
        const int kbase = kt2 * 64;

        // ---- bias prefetch ----
        float4 bias[4][2];
#pragma unroll
        for (int s = 0; s < 4; s++)
#pragma unroll
        for (int n = 0; n < 2; n++) {
            const int kg = (kbase >> 2) + s*4 + quad;
            bias[s][n] = *(const float4*)(Bias2 +
                (((size_t)b*512 + kg)*2048 + qb + n*16 + col)*4);
        }

        __syncthreads();
        // ---- stage K hi/lo planes + V^T (packed u32 copied verbatim) ----
#pragma unroll
        for (int i = 0; i < 4; i++) {
            const int d0 = sc*4 + i*16;
            uint4 ku = *(const uint4*)(Kg + (size_t)(kbase + skey)*64 + d0);
            unsigned ka[4] = {ku.x, ku.y, ku.z, ku.w};
            s4v kh4, kl4;
#pragma unroll
            for (int j = 0; j < 4; j++) {
                kh4[j] = (short)(ka[j] & 0xffffu);
                kl4[j] = (short)(ka[j] >> 16);
            }
            *(s4v*)&Kh[skey*KPAD + d0] = kh4;
            *(s4v*)&Kl[skey*KPAD + d0] = kl4;

            uint4 vu = *(const uint4*)(Vg + (size_t)(kbase + skey)*64 + d0);
            Vt[(d0 + 0)*VPAD + skey] = vu.x;
            Vt[(d0 + 1)*VPAD + skey] = vu.y;
            Vt[(d0 + 2)*VPAD + skey] = vu.z;
            Vt[(d0 + 3)*VPAD + skey] = vu.w;
        }
        __syncthreads();

        // ---- S^T = K·Q^T (3-term hi/lo) ----
        f4v S[4][2];
#pragma unroll
        for (int s = 0; s < 4; s++)
#pragma unroll
            for (int n = 0; n < 2; n++) { f4v z = {0.f,0.f,0.f,0.f}; S[s][n] = z; }
#pragma unroll
        for (int s = 0; s < 4; s++)
#pragma unroll
        for (int c = 0; c < 2; c++) {
            const int off = (s*16 + col)*KPAD + c*32 + quad*8;
            s8v kh = *(const s8v*)&Kh[off];
            s8v kl = *(const s8v*)&Kl[off];
#pragma unroll
            for (int n = 0; n < 2; n++) {
                S[s][n] = mfma32(kh, qfh[n][c], S[s][n]);
                S[s][n] = mfma32(kh, qfl[n][c], S[s][n]);
                S[s][n] = mfma32(kl, qfh[n][c], S[s][n]);
            }
        }

        // ---- bias + online softmax (log2 domain); P^T stays in registers ----
        s4v ph[4][2], pl[4][2];
        float alpha[2];
#pragma unroll
        for (int n = 0; n < 2; n++) {
            float sr[4][4];
            float rmax = -INFINITY;
#pragma unroll
            for (int s = 0; s < 4; s++) {
                float bv[4] = {bias[s][n].x, bias[s][n].y, bias[s][n].z, bias[s][n].w};
#pragma unroll
                for (int r = 0; r < 4; r++) {
                    sr[s][r] = S[s][n][r]*cS + bv[r]*cB;
                    rmax = fmaxf(rmax, sr[s][r]);
                }
            }
            rmax = fmaxf(rmax, __shfl_xor(rmax, 16));
            rmax = fmaxf(rmax, __shfl_xor(rmax, 32));
            const float mnew = fmaxf(mi[n], rmax);
            alpha[n] = exp2f(mi[n] - mnew);
            float rsum = 0.f;
#pragma unroll
            for (int s = 0; s < 4; s++) {
                s4v hh, ll;
#pragma unroll
                for (int r = 0; r < 4; r++) {
                    float pv = exp2f(sr[s][r] - mnew);
                    rsum += pv;
                    union { float f; unsigned u; } uu; uu.f = pv;
                    unsigned short hb = (unsigned short)(uu.u >> 16);
                    hh[r] = (short)hb;
                    ll[r] = (short)f2bf(pv - bf2f(hb));
                }
                ph[s][n] = hh; pl[s][n] = ll;
            }
            rsum += __shfl_xor(rsum, 16);
            rsum += __shfl_xor(rsum, 32);
            li[n] = li[n]*alpha[n] + rsum;
            mi[n] = mnew;
        }

        // ---- rescale O, then O^T += V^T·P^T (3-term) ----
#pragma unroll
        for (int dt = 0; dt < 4; dt++)
#pragma unroll
        for (int n = 0; n < 2; n++)
#pragma unroll
            for (int r = 0; r < 4; r++) Oa[dt][n][r] *= alpha[n];

#pragma unroll
        for (int dt = 0; dt < 4; dt++)
#pragma unroll
        for (int s = 0; s < 4; s++) {
            uint4 u = *(const uint4*)&Vt[(dt*16 + col)*VPAD + s*16 + quad*4];
            unsigned ua[4] = {u.x, u.y, u.z, u.w};
            s4v vh, vl;
#pragma unroll
            for (int j = 0; j < 4; j++) {
                vh[j] = (short)(ua[j] & 0xffffu);
                vl[j] = (short)(ua[j] >> 16);
            }
#pragma unroll
            for (int n = 0; n < 2; n++) {
                Oa[dt][n] = mfma16x16(vh, ph[s][n], Oa[dt][n]);
                Oa[dt][n] = mfma16x16(vl, ph[s][n], Oa[dt][n]);
                Oa[dt][n] = mfma16x16(vh, pl[s][n], Oa[dt][n]);
            }
        }
    }

    // ---- epilogue: O^T -> bf16 hi/lo o-planes (B,N,D) ----
#pragma unroll
    for (int n = 0; n < 2; n++) {
        const float inv = 1.0f / li[n];
        const size_t row = (size_t)b*2048 + qb + n*16 + col;
#pragma unroll
        for (int dt = 0; dt < 4; dt++) {
            s4v hv, lv;
#pragma unroll
            for (int r = 0; r < 4; r++) {
                float y = Oa[dt][n][r] * inv;
                unsigned short hb = f2bf(y);
                hv[r] = (short)hb;
                lv[r] = (short)f2bf(y - bf2f(hb));
            }
            const size_t o = row*1024 + h*64 + dt*16 + quad*4;
            *(s4v*)&Oh[o] = hv;
            *(s4v*)&Ol[o] = lv;
        }
    }
}

// ---------------------------------------------------------------------------
extern "C" void kernel_launch(void* const* d_in, const int* in_sizes, int n_in,
                              void* d_out, int out_size, void* d_ws, size_t ws_size,
                              hipStream_t stream)
{
    const float* x    = (const float*)d_in[0];
    const float* cm   = (const float*)d_in[1];
    const float* im   = (const float*)d_in[2];
    const float* Wqkv = (const float*)d_in[3];
    const float* Wout = (const float*)d_in[4];
    const float* qw   = (const float*)d_in[5];
    const float* kw   = (const float*)d_in[6];
    const float* gate = (const float*)d_in[7];
    float* out = (float*)d_out;

    // ---- workspace layout (bytes) ----
    char* ws = (char*)d_ws;
    unsigned* qp  = (unsigned*)(ws);                      // 16.78 MB packed
    unsigned* kp  = (unsigned*)(ws + 16777216);
    unsigned* vp  = (unsigned*)(ws + 33554432);
    short*    oh  = (short*)   (ws + 50331648);           // 8.39 MB
    short*    ol  = (short*)   (ws + 58720256);
    short*    woh = (short*)   (ws + 67108864);           // 2.10 MB
    short*    wol = (short*)   (ws + 69206016);
    float*    rsb = (float*)   (ws + 71303168);           // 16 KB
    char*     U   = ws + 71319552;                        // union region
    short*    xh  = (short*)(U);                          // 8.39 MB (dead after gemm0)
    short*    xl  = (short*)(U + 8388608);
    short*    wqh = (short*)(U + 16777216);               // 6.29 MB
    short*    wql = (short*)(U + 23068672);
    float*    bias2 = (float*)(U);                        // 33.55 MB (after gemm0)

    // 1) split inputs into bf16 hi/lo planes
    planes_k<<<4096, 256, 0, stream>>>(x,    xh,  xl);
    planes_k<<<3072, 256, 0, stream>>>(Wqkv, wqh, wql);
    planes_k<<<1024, 256, 0, stream>>>(Wout, woh, wol);
    // 2) qkv projection (MFMA) -> packed q/k/v planes, head-scattered
    gemm_mfma<0><<<dim3(24, 32), 256, 0, stream>>>(xh, xl, wqh, wql,
                                                   qp, kp, vp, nullptr);
    // 3) rmsnorm q, k (in place on packed planes)
    rmsnorm_p<<<16384, 256, 0, stream>>>(qp, qw);
    rmsnorm_p<<<16384, 256, 0, stream>>>(kp, kw);
    // 4) bias precompute (overwrites x/wq plane region — they are dead now)
    rowscale_k<<<64, 256, 0, stream>>>(cm, rsb);
    bias_pre<<<256, 256, 0, stream>>>(cm, im, rsb, bias2);
    // 5) flash attention -> bf16 o-planes
    attn_mfma<<<512, 256, 0, stream>>>(qp, kp, vp, bias2, gate, oh, ol);
    // 6) output projection (MFMA) -> fp32 out
    gemm_mfma<1><<<dim3(8, 32), 256, 0, stream>>>(oh, ol, woh, wol,
                                                  nullptr, nullptr, nullptr, out);
}

// Round 5
// 426.712 us; speedup vs baseline: 2.7516x; 1.1193x over previous
//
#include <hip/hip_runtime.h>
#include <math.h>

// Problem constants: B=2, N=2048, D=1024, H=16, HD=64, C=4

typedef __attribute__((ext_vector_type(8))) short s8v;
typedef __attribute__((ext_vector_type(4))) short s4v;
typedef __attribute__((ext_vector_type(4))) float f4v;

#define L2E 1.44269504088896340736f

__device__ __forceinline__ unsigned short f2bf(float x) {
    union { float f; unsigned u; } v; v.f = x;
    unsigned r = v.u + 0x7FFF + ((v.u >> 16) & 1);
    return (unsigned short)(r >> 16);
}
__device__ __forceinline__ float bf2f(unsigned short h) {
    union { unsigned u; float f; } v; v.u = ((unsigned)h) << 16;
    return v.f;
}
__device__ __forceinline__ f4v mfma32(s8v a, s8v b, f4v c) {
    return __builtin_amdgcn_mfma_f32_16x16x32_bf16(a, b, c, 0, 0, 0);
}
__device__ __forceinline__ f4v mfma16x16(s4v a, s4v b, f4v c) {
    return __builtin_amdgcn_mfma_f32_16x16x16bf16_1k(a, b, c, 0, 0, 0);
}
__device__ __forceinline__ void gl_lds16(const void* g, void* l) {
    __builtin_amdgcn_global_load_lds(
        (const __attribute__((address_space(1))) unsigned*)g,
        (__attribute__((address_space(3))) unsigned*)l, 16, 0, 0);
}

// ---------------------------------------------------------------------------
// Split fp32 tensor into bf16 hi/lo planes.
// ---------------------------------------------------------------------------
__global__ __launch_bounds__(256)
void planes_k(const float* __restrict__ src, short* __restrict__ ph,
              short* __restrict__ pl)
{
    const int i = blockIdx.x * 256 + threadIdx.x;
    float4 f = ((const float4*)src)[i];
    float fa[4] = {f.x, f.y, f.z, f.w};
    s4v h4, l4;
#pragma unroll
    for (int j = 0; j < 4; j++) {
        unsigned short hb = f2bf(fa[j]);
        h4[j] = (short)hb;
        l4[j] = (short)f2bf(fa[j] - bf2f(hb));
    }
    ((s4v*)ph)[i] = h4;
    ((s4v*)pl)[i] = l4;
}

// ---------------------------------------------------------------------------
// MFMA GEMM  C[M,NC] = A[M,1024] * B[NC,1024]^T  from bf16 hi/lo planes.
// 3-term split: Ah*Bh + Ah*Bl + Al*Bh.  128x128 tile, BK=64, 16 iters.
// MODE 0: fused RMSNorm (q/k cols only) + scatter -> packed u32 q/k/v planes.
// MODE 1: plain fp32 row-major Cout.
// ---------------------------------------------------------------------------
template<int MODE>
__global__ __launch_bounds__(256, 2)
void gemm_mfma(const short* __restrict__ Ah, const short* __restrict__ Al,
               const short* __restrict__ Bh, const short* __restrict__ Bl,
               unsigned* __restrict__ Pq, unsigned* __restrict__ Pk,
               unsigned* __restrict__ Pv, float* __restrict__ Cout,
               const float* __restrict__ qw, const float* __restrict__ kw)
{
    __shared__ short sAh[128*64], sAl[128*64], sBh[128*64], sBl[128*64];

    const int t    = threadIdx.x;
    const int w    = t >> 6;
    const int lane = t & 63;
    const int wm   = w >> 1, wn = w & 1;
    const int col  = lane & 15, quad = lane >> 4;
    const int m0   = blockIdx.y * 128;
    const int n0   = blockIdx.x * 128;

    f4v acc[4][4];
#pragma unroll
    for (int i = 0; i < 4; i++)
#pragma unroll
        for (int j = 0; j < 4; j++) { f4v z = {0.f,0.f,0.f,0.f}; acc[i][j] = z; }

    const int srow   = w*32 + (lane >> 3);
    const int schunk = ((lane & 7) ^ (lane >> 3)) * 8;
    const short* agh = Ah + (size_t)(m0 + srow)*1024 + schunk;
    const short* agl = Al + (size_t)(m0 + srow)*1024 + schunk;
    const short* bgh = Bh + (size_t)(n0 + srow)*1024 + schunk;
    const short* bgl = Bl + (size_t)(n0 + srow)*1024 + schunk;
    const int sbase = (w*32) * 64;

    for (int kt = 0; kt < 16; kt++) {
        const int k0 = kt * 64;
        __syncthreads();
#pragma unroll
        for (int j = 0; j < 4; j++) {
            gl_lds16(agh + k0 + j*8*1024, &sAh[sbase + j*8*64]);
            gl_lds16(agl + k0 + j*8*1024, &sAl[sbase + j*8*64]);
            gl_lds16(bgh + k0 + j*8*1024, &sBh[sbase + j*8*64]);
            gl_lds16(bgl + k0 + j*8*1024, &sBl[sbase + j*8*64]);
        }
        __syncthreads();
#pragma unroll
        for (int kc = 0; kc < 2; kc++) {
            s8v ahf[4], alf[4], bhf[4], blf[4];
            const int sw = ((kc*4 + quad) ^ (col & 7)) * 8;
#pragma unroll
            for (int i = 0; i < 4; i++) {
                const int aoff = (wm*64 + i*16 + col)*64 + sw;
                ahf[i] = *(const s8v*)&sAh[aoff];
                alf[i] = *(const s8v*)&sAl[aoff];
                const int boff = (wn*64 + i*16 + col)*64 + sw;
                bhf[i] = *(const s8v*)&sBh[boff];
                blf[i] = *(const s8v*)&sBl[boff];
            }
#pragma unroll
            for (int i = 0; i < 4; i++)
#pragma unroll
            for (int j = 0; j < 4; j++) {
                acc[i][j] = mfma32(ahf[i], bhf[j], acc[i][j]);
                acc[i][j] = mfma32(ahf[i], blf[j], acc[i][j]);
                acc[i][j] = mfma32(alf[i], bhf[j], acc[i][j]);
            }
        }
    }

    if (MODE == 0) {
        // fused RMSNorm over HD=64: one wave holds full 64-col head rows.
        const int whichW = (n0 + wn*64) >> 10;      // wave-uniform: 0=q,1=k,2=v
        if (whichW < 2) {
            const float* nw = (whichW == 0) ? qw : kw;
            float wj[4];
#pragma unroll
            for (int j = 0; j < 4; j++) wj[j] = nw[j*16 + col];
#pragma unroll
            for (int i = 0; i < 4; i++)
#pragma unroll
            for (int r = 0; r < 4; r++) {
                float s2 = acc[i][0][r]*acc[i][0][r] + acc[i][1][r]*acc[i][1][r]
                         + acc[i][2][r]*acc[i][2][r] + acc[i][3][r]*acc[i][3][r];
                s2 += __shfl_xor(s2, 1);
                s2 += __shfl_xor(s2, 2);
                s2 += __shfl_xor(s2, 4);
                s2 += __shfl_xor(s2, 8);
                const float scn = rsqrtf(s2*(1.0f/64.0f) + 1e-6f);
#pragma unroll
                for (int j = 0; j < 4; j++) acc[i][j][r] *= scn*wj[j];
            }
        }
    }

#pragma unroll
    for (int i = 0; i < 4; i++)
#pragma unroll
    for (int j = 0; j < 4; j++) {
        const int gcol = n0 + wn*64 + j*16 + col;
#pragma unroll
        for (int r = 0; r < 4; r++) {
            const int grow = m0 + wm*64 + i*16 + quad*4 + r;
            const float v = acc[i][j][r];
            if (MODE == 0) {
                const int which = gcol >> 10;
                const int hh = (gcol >> 6) & 15;
                const int hd = gcol & 63;
                const int b = grow >> 11, nn = grow & 2047;
                unsigned* dst = which == 0 ? Pq : (which == 1 ? Pk : Pv);
                unsigned short hb = f2bf(v);
                union { float f; unsigned u; } rr; rr.f = v - bf2f(hb);
                dst[((size_t)(b*16 + hh)*2048 + nn)*64 + hd] =
                    (unsigned)hb | (rr.u & 0xffff0000u);
            } else {
                Cout[(size_t)grow*1024 + gcol] = v;
            }
        }
    }
}

// ---------------------------------------------------------------------------
// rowscale[b,q] = 1 / max(max_k dot4(cm[b,:,q], cm[b,:,k]), 1e-6)
// ---------------------------------------------------------------------------
__global__ __launch_bounds__(256)
void rowscale_k(const float* __restrict__ cm, float* __restrict__ rs)
{
    __shared__ float cms[4][2048];
    const int b  = blockIdx.x >> 5;
    const int qt = blockIdx.x & 31;
    const float* base = cm + (size_t)b * 4 * 2048;
    for (int i = threadIdx.x; i < 2048; i += 256) {
        cms[0][i] = base[i];
        cms[1][i] = base[2048 + i];
        cms[2][i] = base[4096 + i];
        cms[3][i] = base[6144 + i];
    }
    __syncthreads();
    const int q    = qt * 64 + (threadIdx.x >> 2);
    const int part = threadIdx.x & 3;
    const float a0 = cms[0][q], a1 = cms[1][q], a2 = cms[2][q], a3 = cms[3][q];
    float mx = 0.f;
    for (int i = 0; i < 512; i++) {
        const int k = part + 4 * i;
        float d = a0*cms[0][k] + a1*cms[1][k] + a2*cms[2][k] + a3*cms[3][k];
        mx = fmaxf(mx, d);
    }
    mx = fmaxf(mx, __shfl_xor(mx, 1));
    mx = fmaxf(mx, __shfl_xor(mx, 2));
    if (part == 0) rs[b * 2048 + q] = 1.0f / fmaxf(mx, 1e-6f);
}

// ---------------------------------------------------------------------------
// Bias precompute:  Bias2[b][k>>2][q][k&3] = (dot4(cm_q,cm_k)*rsq - 0.5)*2
//                                            + 0.3*im[b][q][k]
// ---------------------------------------------------------------------------
__global__ __launch_bounds__(256)
void bias_pre(const float* __restrict__ cm, const float* __restrict__ im,
              const float* __restrict__ rs, float* __restrict__ Bias2)
{
    const int bid = blockIdx.x;
    const int qq = bid & 3;
    const int kt = (bid >> 2) & 31;
    const int b  = bid >> 7;

    __shared__ float cmk[4][64];
    const int t = threadIdx.x;
    const int k0 = kt * 64;
    cmk[t >> 6][t & 63] = cm[(size_t)b*8192 + (t >> 6)*2048 + k0 + (t & 63)];
    __syncthreads();

    const int klane = t & 15;
    const int qrow  = t >> 4;
    const int kk = k0 + klane*4;
    const int kg = kk >> 2;
    float ck[4][4];
#pragma unroll
    for (int c = 0; c < 4; c++)
#pragma unroll
        for (int j = 0; j < 4; j++) ck[c][j] = cmk[c][klane*4 + j];

    const float* cmb = cm + (size_t)b * 8192;
    for (int it = 0; it < 32; it++) {
        const int q = qq*512 + it*16 + qrow;
        float4 imv = *(const float4*)(im + ((size_t)b*2048 + q)*2048 + kk);
        const float rsq = rs[b*2048 + q];
        const float c0 = cmb[q], c1 = cmb[2048+q], c2 = cmb[4096+q], c3 = cmb[6144+q];
        float o[4];
        float iv[4] = {imv.x, imv.y, imv.z, imv.w};
#pragma unroll
        for (int j = 0; j < 4; j++) {
            float same = c0*ck[0][j] + c1*ck[1][j] + c2*ck[2][j] + c3*ck[3][j];
            o[j] = (same*rsq - 0.5f)*2.0f + 0.3f*iv[j];
        }
        *(float4*)(Bias2 + (((size_t)b*512 + kg)*2048 + q)*4) =
            make_float4(o[0], o[1], o[2], o[3]);
    }
}

// ---------------------------------------------------------------------------
// Flash attention, S^T orientation, software-pipelined staging:
// K/V tile kt+1 is register-prefetched during compute of tile kt, so no
// global-load latency sits between the two barriers.  Bias loads are issued
// BEFORE the prefetch so their s_waitcnt is vmcnt(8), not vmcnt(0).
// ---------------------------------------------------------------------------
#define KPAD 72   // shorts per K-plane row
#define VPAD 68   // u32 per Vt row

__global__ __launch_bounds__(256, 2)
void attn_mfma(const unsigned* __restrict__ Qp, const unsigned* __restrict__ Kp,
               const unsigned* __restrict__ Vp, const float* __restrict__ Bias2,
               const float* __restrict__ gate, short* __restrict__ Oh,
               short* __restrict__ Ol)
{
    const int bid = blockIdx.x;
    const int h  = bid & 15;
    const int qt = (bid >> 4) & 15;
    const int b  = bid >> 8;

    __shared__ __align__(16) short    Kh[64*KPAD];
    __shared__ __align__(16) short    Kl[64*KPAD];
    __shared__ __align__(16) unsigned Vt[64*VPAD];   // [d][key], hi | lo<<16

    const int t    = threadIdx.x;
    const int w    = t >> 6;
    const int lane = t & 63;
    const int col  = lane & 15;
    const int quad = lane >> 4;

    const size_t headoff = ((size_t)(b*16 + h)) * 2048 * 64;
    const unsigned* Qh = Qp + headoff;
    const unsigned* Kg = Kp + headoff;
    const unsigned* Vg = Vp + headoff;

    const int qb = qt*128 + w*32;

    // ---- Q B-fragments (hi/lo) from packed planes ----
    s8v qfh[2][2], qfl[2][2];
#pragma unroll
    for (int n = 0; n < 2; n++)
#pragma unroll
    for (int c = 0; c < 2; c++) {
        const unsigned* p = Qh + (size_t)(qb + n*16 + col)*64 + c*32 + quad*8;
        uint4 u0 = *(const uint4*)p;
        uint4 u1 = *(const uint4*)(p + 4);
        unsigned ua[8] = {u0.x,u0.y,u0.z,u0.w, u1.x,u1.y,u1.z,u1.w};
        s8v hi, lo;
#pragma unroll
        for (int j = 0; j < 8; j++) {
            hi[j] = (short)(ua[j] & 0xffffu);
            lo[j] = (short)(ua[j] >> 16);
        }
        qfh[n][c] = hi; qfl[n][c] = lo;
    }

    const float g  = fminf(fmaxf(gate[h], 0.f), 1.f);
    const float cS = 0.125f * L2E;
    const float cB = 3.0f * g * L2E;

    float mi[2] = {-INFINITY, -INFINITY};
    float li[2] = {0.f, 0.f};
    f4v Oa[4][2];
#pragma unroll
    for (int dt = 0; dt < 4; dt++)
#pragma unroll
        for (int n = 0; n < 2; n++) { f4v z = {0.f,0.f,0.f,0.f}; Oa[dt][n] = z; }

    const int skey = t >> 2;
    const int sc   = t & 3;

    // ---- prologue: fetch tile 0, stage to LDS ----
    uint4 kr[4], vr[4];
#pragma unroll
    for (int i = 0; i < 4; i++) {
        kr[i] = *(const uint4*)(Kg + (size_t)skey*64 + sc*4 + i*16);
        vr[i] = *(const uint4*)(Vg + (size_t)skey*64 + sc*4 + i*16);
    }
#pragma unroll
    for (int i = 0; i < 4; i++) {
        const int d0 = sc*4 + i*16;
        unsigned ka[4] = {kr[i].x, kr[i].y, kr[i].z, kr[i].w};
        s4v kh4, kl4;
#pragma unroll
        for (int j = 0; j < 4; j++) {
            kh4[j] = (short)(ka[j] & 0xffffu);
            kl4[j] = (short)(ka[j] >> 16);
        }
        *(s4v*)&Kh[skey*KPAD + d0] = kh4;
        *(s4v*)&Kl[skey*KPAD + d0] = kl4;
        Vt[(d0 + 0)*VPAD + skey] = vr[i].x;
        Vt[(d0 + 1)*VPAD + skey] = vr[i].y;
        Vt[(d0 + 2)*VPAD + skey] = vr[i].z;
        Vt[(d0 + 3)*VPAD + skey] = vr[i].w;
    }
    __syncthreads();

    for (int kt2 = 0; kt2 < 32; kt2++) {
        const int kbase = kt2 * 64;

        // ---- bias loads FIRST (oldest outstanding -> vmcnt(8) at use) ----
        float4 bias[4][2];
#pragma unroll
        for (int s = 0; s < 4; s++)
#pragma unroll
        for (int n = 0; n < 2; n++) {
            const int kg = (kbase >> 2) + s*4 + quad;
            bias[s][n] = *(const float4*)(Bias2 +
                (((size_t)b*512 + kg)*2048 + qb + n*16 + col)*4);
        }
        // ---- prefetch next K/V tile into registers ----
        if (kt2 < 31) {
            const int nb = kbase + 64;
#pragma unroll
            for (int i = 0; i < 4; i++) {
                kr[i] = *(const uint4*)(Kg + (size_t)(nb + skey)*64 + sc*4 + i*16);
                vr[i] = *(const uint4*)(Vg + (size_t)(nb + skey)*64 + sc*4 + i*16);
            }
        }

        // ---- S^T = K·Q^T (3-term hi/lo) ----
        f4v S[4][2];
#pragma unroll
        for (int s = 0; s < 4; s++)
#pragma unroll
            for (int n = 0; n < 2; n++) { f4v z = {0.f,0.f,0.f,0.f}; S[s][n] = z; }
#pragma unroll
        for (int s = 0; s < 4; s++)
#pragma unroll
        for (int c = 0; c < 2; c++) {
            const int off = (s*16 + col)*KPAD + c*32 + quad*8;
            s8v kh = *(const s8v*)&Kh[off];
            s8v kl = *(const s8v*)&Kl[off];
#pragma unroll
            for (int n = 0; n < 2; n++) {
                S[s][n] = mfma32(kh, qfh[n][c], S[s][n]);
                S[s][n] = mfma32(kh, qfl[n][c], S[s][n]);
                S[s][n] = mfma32(kl, qfh[n][c], S[s][n]);
            }
        }

        // ---- bias + online softmax (log2 domain); P^T stays in registers ----
        s4v ph[4][2], pl[4][2];
        float alpha[2];
#pragma unroll
        for (int n = 0; n < 2; n++) {
            float sr[4][4];
            float rmax = -INFINITY;
#pragma unroll
            for (int s = 0; s < 4; s++) {
                float bv[4] = {bias[s][n].x, bias[s][n].y, bias[s][n].z, bias[s][n].w};
#pragma unroll
                for (int r = 0; r < 4; r++) {
                    sr[s][r] = S[s][n][r]*cS + bv[r]*cB;
                    rmax = fmaxf(rmax, sr[s][r]);
                }
            }
            rmax = fmaxf(rmax, __shfl_xor(rmax, 16));
            rmax = fmaxf(rmax, __shfl_xor(rmax, 32));
            const float mnew = fmaxf(mi[n], rmax);
            alpha[n] = exp2f(mi[n] - mnew);
            float rsum = 0.f;
#pragma unroll
            for (int s = 0; s < 4; s++) {
                s4v hh, ll;
#pragma unroll
                for (int r = 0; r < 4; r++) {
                    float pv = exp2f(sr[s][r] - mnew);
                    rsum += pv;
                    union { float f; unsigned u; } uu; uu.f = pv;
                    unsigned short hb = (unsigned short)(uu.u >> 16);  // trunc hi
                    hh[r] = (short)hb;
                    union { float f; unsigned u; } r2; r2.f = pv - bf2f(hb);
                    ll[r] = (short)(r2.u >> 16);                       // trunc lo
                }
                ph[s][n] = hh; pl[s][n] = ll;
            }
            rsum += __shfl_xor(rsum, 16);
            rsum += __shfl_xor(rsum, 32);
            li[n] = li[n]*alpha[n] + rsum;
            mi[n] = mnew;
        }

        // ---- rescale O, then O^T += V^T·P^T (3-term) ----
#pragma unroll
        for (int dt = 0; dt < 4; dt++)
#pragma unroll
        for (int n = 0; n < 2; n++)
#pragma unroll
            for (int r = 0; r < 4; r++) Oa[dt][n][r] *= alpha[n];

#pragma unroll
        for (int dt = 0; dt < 4; dt++)
#pragma unroll
        for (int s = 0; s < 4; s++) {
            uint4 u = *(const uint4*)&Vt[(dt*16 + col)*VPAD + s*16 + quad*4];
            unsigned ua[4] = {u.x, u.y, u.z, u.w};
            s4v vh, vl;
#pragma unroll
            for (int j = 0; j < 4; j++) {
                vh[j] = (short)(ua[j] & 0xffffu);
                vl[j] = (short)(ua[j] >> 16);
            }
#pragma unroll
            for (int n = 0; n < 2; n++) {
                Oa[dt][n] = mfma16x16(vh, ph[s][n], Oa[dt][n]);
                Oa[dt][n] = mfma16x16(vl, ph[s][n], Oa[dt][n]);
                Oa[dt][n] = mfma16x16(vh, pl[s][n], Oa[dt][n]);
            }
        }

        // ---- drain compute, then write prefetched tile to LDS ----
        if (kt2 < 31) {
            __syncthreads();
#pragma unroll
            for (int i = 0; i < 4; i++) {
                const int d0 = sc*4 + i*16;
                unsigned ka[4] = {kr[i].x, kr[i].y, kr[i].z, kr[i].w};
                s4v kh4, kl4;
#pragma unroll
                for (int j = 0; j < 4; j++) {
                    kh4[j] = (short)(ka[j] & 0xffffu);
                    kl4[j] = (short)(ka[j] >> 16);
                }
                *(s4v*)&Kh[skey*KPAD + d0] = kh4;
                *(s4v*)&Kl[skey*KPAD + d0] = kl4;
                Vt[(d0 + 0)*VPAD + skey] = vr[i].x;
                Vt[(d0 + 1)*VPAD + skey] = vr[i].y;
                Vt[(d0 + 2)*VPAD + skey] = vr[i].z;
                Vt[(d0 + 3)*VPAD + skey] = vr[i].w;
            }
            __syncthreads();
        }
    }

    // ---- epilogue: O^T -> bf16 hi/lo o-planes (B,N,D) ----
#pragma unroll
    for (int n = 0; n < 2; n++) {
        const float inv = 1.0f / li[n];
        const size_t row = (size_t)b*2048 + qb + n*16 + col;
#pragma unroll
        for (int dt = 0; dt < 4; dt++) {
            s4v hv, lv;
#pragma unroll
            for (int r = 0; r < 4; r++) {
                float y = Oa[dt][n][r] * inv;
                unsigned short hb = f2bf(y);
                hv[r] = (short)hb;
                union { float f; unsigned u; } rr; rr.f = y - bf2f(hb);
                lv[r] = (short)(rr.u >> 16);
            }
            const size_t o = row*1024 + h*64 + dt*16 + quad*4;
            *(s4v*)&Oh[o] = hv;
            *(s4v*)&Ol[o] = lv;
        }
    }
}

// ---------------------------------------------------------------------------
extern "C" void kernel_launch(void* const* d_in, const int* in_sizes, int n_in,
                              void* d_out, int out_size, void* d_ws, size_t ws_size,
                              hipStream_t stream)
{
    const float* x    = (const float*)d_in[0];
    const float* cm   = (const float*)d_in[1];
    const float* im   = (const float*)d_in[2];
    const float* Wqkv = (const float*)d_in[3];
    const float* Wout = (const float*)d_in[4];
    const float* qw   = (const float*)d_in[5];
    const float* kw   = (const float*)d_in[6];
    const float* gate = (const float*)d_in[7];
    float* out = (float*)d_out;

    // ---- workspace layout (bytes) ----
    char* ws = (char*)d_ws;
    unsigned* qp  = (unsigned*)(ws);                      // 16.78 MB packed
    unsigned* kp  = (unsigned*)(ws + 16777216);
    unsigned* vp  = (unsigned*)(ws + 33554432);
    short*    oh  = (short*)   (ws + 50331648);           // 8.39 MB
    short*    ol  = (short*)   (ws + 58720256);
    short*    woh = (short*)   (ws + 67108864);           // 2.10 MB
    short*    wol = (short*)   (ws + 69206016);
    float*    rsb = (float*)   (ws + 71303168);           // 16 KB
    char*     U   = ws + 71319552;                        // union region
    short*    xh  = (short*)(U);                          // 8.39 MB (dead after gemm0)
    short*    xl  = (short*)(U + 8388608);
    short*    wqh = (short*)(U + 16777216);               // 6.29 MB
    short*    wql = (short*)(U + 23068672);
    float*    bias2 = (float*)(U);                        // 33.55 MB (after gemm0)

    // 1) split inputs into bf16 hi/lo planes
    planes_k<<<4096, 256, 0, stream>>>(x,    xh,  xl);
    planes_k<<<3072, 256, 0, stream>>>(Wqkv, wqh, wql);
    planes_k<<<1024, 256, 0, stream>>>(Wout, woh, wol);
    // 2) qkv projection (MFMA) + fused rmsnorm -> packed q/k/v planes
    gemm_mfma<0><<<dim3(24, 32), 256, 0, stream>>>(xh, xl, wqh, wql,
                                                   qp, kp, vp, nullptr, qw, kw);
    // 3) bias precompute (overwrites x/wq plane region — dead after gemm0)
    rowscale_k<<<64, 256, 0, stream>>>(cm, rsb);
    bias_pre<<<256, 256, 0, stream>>>(cm, im, rsb, bias2);
    // 4) flash attention -> bf16 o-planes
    attn_mfma<<<512, 256, 0, stream>>>(qp, kp, vp, bias2, gate, oh, ol);
    // 5) output projection (MFMA) -> fp32 out
    gemm_mfma<1><<<dim3(8, 32), 256, 0, stream>>>(oh, ol, woh, wol,
                                                  nullptr, nullptr, nullptr, out,
                                                  nullptr, nullptr);
}

// Round 6
// 408.236 us; speedup vs baseline: 2.8761x; 1.0453x over previous
//
#include <hip/hip_runtime.h>
#include <math.h>

// Problem constants: B=2, N=2048, D=1024, H=16, HD=64, C=4

typedef __attribute__((ext_vector_type(8))) short s8v;
typedef __attribute__((ext_vector_type(4))) short s4v;
typedef __attribute__((ext_vector_type(4))) float f4v;

#define L2E 1.44269504088896340736f

__device__ __forceinline__ unsigned short f2bf(float x) {
    union { float f; unsigned u; } v; v.f = x;
    unsigned r = v.u + 0x7FFF + ((v.u >> 16) & 1);
    return (unsigned short)(r >> 16);
}
__device__ __forceinline__ float bf2f(unsigned short h) {
    union { unsigned u; float f; } v; v.u = ((unsigned)h) << 16;
    return v.f;
}
__device__ __forceinline__ f4v mfma32(s8v a, s8v b, f4v c) {
    return __builtin_amdgcn_mfma_f32_16x16x32_bf16(a, b, c, 0, 0, 0);
}
__device__ __forceinline__ f4v mfma16x16(s4v a, s4v b, f4v c) {
    return __builtin_amdgcn_mfma_f32_16x16x16bf16_1k(a, b, c, 0, 0, 0);
}
__device__ __forceinline__ void gl_lds16(const void* g, void* l) {
    __builtin_amdgcn_global_load_lds(
        (const __attribute__((address_space(1))) unsigned*)g,
        (__attribute__((address_space(3))) unsigned*)l, 16, 0, 0);
}

// ---------------------------------------------------------------------------
// Split fp32 tensor into bf16 hi/lo planes.
// ---------------------------------------------------------------------------
__global__ __launch_bounds__(256)
void planes_k(const float* __restrict__ src, short* __restrict__ ph,
              short* __restrict__ pl)
{
    const int i = blockIdx.x * 256 + threadIdx.x;
    float4 f = ((const float4*)src)[i];
    float fa[4] = {f.x, f.y, f.z, f.w};
    s4v h4, l4;
#pragma unroll
    for (int j = 0; j < 4; j++) {
        unsigned short hb = f2bf(fa[j]);
        h4[j] = (short)hb;
        l4[j] = (short)f2bf(fa[j] - bf2f(hb));
    }
    ((s4v*)ph)[i] = h4;
    ((s4v*)pl)[i] = l4;
}

// ---------------------------------------------------------------------------
// MFMA GEMM  C[M,NC] = A[M,1024] * B[NC,1024]^T  from bf16 hi/lo planes.
// MODE 0: fused RMSNorm (q/k) + scatter -> packed u32 q/k planes, bf16 v plane.
// MODE 1: plain fp32 row-major Cout.
// ---------------------------------------------------------------------------
template<int MODE>
__global__ __launch_bounds__(256, 2)
void gemm_mfma(const short* __restrict__ Ah, const short* __restrict__ Al,
               const short* __restrict__ Bh, const short* __restrict__ Bl,
               unsigned* __restrict__ Pq, unsigned* __restrict__ Pk,
               short* __restrict__ Pv16, float* __restrict__ Cout,
               const float* __restrict__ qw, const float* __restrict__ kw)
{
    __shared__ short sAh[128*64], sAl[128*64], sBh[128*64], sBl[128*64];

    const int t    = threadIdx.x;
    const int w    = t >> 6;
    const int lane = t & 63;
    const int wm   = w >> 1, wn = w & 1;
    const int col  = lane & 15, quad = lane >> 4;
    const int m0   = blockIdx.y * 128;
    const int n0   = blockIdx.x * 128;

    f4v acc[4][4];
#pragma unroll
    for (int i = 0; i < 4; i++)
#pragma unroll
        for (int j = 0; j < 4; j++) { f4v z = {0.f,0.f,0.f,0.f}; acc[i][j] = z; }

    const int srow   = w*32 + (lane >> 3);
    const int schunk = ((lane & 7) ^ (lane >> 3)) * 8;
    const short* agh = Ah + (size_t)(m0 + srow)*1024 + schunk;
    const short* agl = Al + (size_t)(m0 + srow)*1024 + schunk;
    const short* bgh = Bh + (size_t)(n0 + srow)*1024 + schunk;
    const short* bgl = Bl + (size_t)(n0 + srow)*1024 + schunk;
    const int sbase = (w*32) * 64;

    for (int kt = 0; kt < 16; kt++) {
        const int k0 = kt * 64;
        __syncthreads();
#pragma unroll
        for (int j = 0; j < 4; j++) {
            gl_lds16(agh + k0 + j*8*1024, &sAh[sbase + j*8*64]);
            gl_lds16(agl + k0 + j*8*1024, &sAl[sbase + j*8*64]);
            gl_lds16(bgh + k0 + j*8*1024, &sBh[sbase + j*8*64]);
            gl_lds16(bgl + k0 + j*8*1024, &sBl[sbase + j*8*64]);
        }
        __syncthreads();
#pragma unroll
        for (int kc = 0; kc < 2; kc++) {
            s8v ahf[4], alf[4], bhf[4], blf[4];
            const int sw = ((kc*4 + quad) ^ (col & 7)) * 8;
#pragma unroll
            for (int i = 0; i < 4; i++) {
                const int aoff = (wm*64 + i*16 + col)*64 + sw;
                ahf[i] = *(const s8v*)&sAh[aoff];
                alf[i] = *(const s8v*)&sAl[aoff];
                const int boff = (wn*64 + i*16 + col)*64 + sw;
                bhf[i] = *(const s8v*)&sBh[boff];
                blf[i] = *(const s8v*)&sBl[boff];
            }
#pragma unroll
            for (int i = 0; i < 4; i++)
#pragma unroll
            for (int j = 0; j < 4; j++) {
                acc[i][j] = mfma32(ahf[i], bhf[j], acc[i][j]);
                acc[i][j] = mfma32(ahf[i], blf[j], acc[i][j]);
                acc[i][j] = mfma32(alf[i], bhf[j], acc[i][j]);
            }
        }
    }

    if (MODE == 0) {
        // fused RMSNorm over HD=64: one wave holds full 64-col head rows.
        const int whichW = (n0 + wn*64) >> 10;      // wave-uniform: 0=q,1=k,2=v
        if (whichW < 2) {
            const float* nw = (whichW == 0) ? qw : kw;
            float wj[4];
#pragma unroll
            for (int j = 0; j < 4; j++) wj[j] = nw[j*16 + col];
#pragma unroll
            for (int i = 0; i < 4; i++)
#pragma unroll
            for (int r = 0; r < 4; r++) {
                float s2 = acc[i][0][r]*acc[i][0][r] + acc[i][1][r]*acc[i][1][r]
                         + acc[i][2][r]*acc[i][2][r] + acc[i][3][r]*acc[i][3][r];
                s2 += __shfl_xor(s2, 1);
                s2 += __shfl_xor(s2, 2);
                s2 += __shfl_xor(s2, 4);
                s2 += __shfl_xor(s2, 8);
                const float scn = rsqrtf(s2*(1.0f/64.0f) + 1e-6f);
#pragma unroll
                for (int j = 0; j < 4; j++) acc[i][j][r] *= scn*wj[j];
            }
        }
    }

#pragma unroll
    for (int i = 0; i < 4; i++)
#pragma unroll
    for (int j = 0; j < 4; j++) {
        const int gcol = n0 + wn*64 + j*16 + col;
#pragma unroll
        for (int r = 0; r < 4; r++) {
            const int grow = m0 + wm*64 + i*16 + quad*4 + r;
            const float v = acc[i][j][r];
            if (MODE == 0) {
                const int which = gcol >> 10;
                const int hh = (gcol >> 6) & 15;
                const int hd = gcol & 63;
                const int b = grow >> 11, nn = grow & 2047;
                const size_t idx = ((size_t)(b*16 + hh)*2048 + nn)*64 + hd;
                if (which == 2) {
                    Pv16[idx] = (short)f2bf(v);          // rounded bf16 V
                } else {
                    unsigned* dst = which == 0 ? Pq : Pk;
                    unsigned short hb = f2bf(v);
                    union { float f; unsigned u; } rr; rr.f = v - bf2f(hb);
                    dst[idx] = (unsigned)hb | (rr.u & 0xffff0000u);
                }
            } else {
                Cout[(size_t)grow*1024 + gcol] = v;
            }
        }
    }
}

// ---------------------------------------------------------------------------
// rowscale[b,q] = 1 / max(max_k dot4(cm[b,:,q], cm[b,:,k]), 1e-6)
// ---------------------------------------------------------------------------
__global__ __launch_bounds__(256)
void rowscale_k(const float* __restrict__ cm, float* __restrict__ rs)
{
    __shared__ float cms[4][2048];
    const int b  = blockIdx.x >> 5;
    const int qt = blockIdx.x & 31;
    const float* base = cm + (size_t)b * 4 * 2048;
    for (int i = threadIdx.x; i < 2048; i += 256) {
        cms[0][i] = base[i];
        cms[1][i] = base[2048 + i];
        cms[2][i] = base[4096 + i];
        cms[3][i] = base[6144 + i];
    }
    __syncthreads();
    const int q    = qt * 64 + (threadIdx.x >> 2);
    const int part = threadIdx.x & 3;
    const float a0 = cms[0][q], a1 = cms[1][q], a2 = cms[2][q], a3 = cms[3][q];
    float mx = 0.f;
    for (int i = 0; i < 512; i++) {
        const int k = part + 4 * i;
        float d = a0*cms[0][k] + a1*cms[1][k] + a2*cms[2][k] + a3*cms[3][k];
        mx = fmaxf(mx, d);
    }
    mx = fmaxf(mx, __shfl_xor(mx, 1));
    mx = fmaxf(mx, __shfl_xor(mx, 2));
    if (part == 0) rs[b * 2048 + q] = 1.0f / fmaxf(mx, 1e-6f);
}

// ---------------------------------------------------------------------------
// Bias precompute:  Bias2[b][k>>2][q][k&3] = (dot4(cm_q,cm_k)*rsq - 0.5)*2
//                                            + 0.3*im[b][q][k]
// ---------------------------------------------------------------------------
__global__ __launch_bounds__(256)
void bias_pre(const float* __restrict__ cm, const float* __restrict__ im,
              const float* __restrict__ rs, float* __restrict__ Bias2)
{
    const int bid = blockIdx.x;
    const int qq = bid & 3;
    const int kt = (bid >> 2) & 31;
    const int b  = bid >> 7;

    __shared__ float cmk[4][64];
    const int t = threadIdx.x;
    const int k0 = kt * 64;
    cmk[t >> 6][t & 63] = cm[(size_t)b*8192 + (t >> 6)*2048 + k0 + (t & 63)];
    __syncthreads();

    const int klane = t & 15;
    const int qrow  = t >> 4;
    const int kk = k0 + klane*4;
    const int kg = kk >> 2;
    float ck[4][4];
#pragma unroll
    for (int c = 0; c < 4; c++)
#pragma unroll
        for (int j = 0; j < 4; j++) ck[c][j] = cmk[c][klane*4 + j];

    const float* cmb = cm + (size_t)b * 8192;
    for (int it = 0; it < 32; it++) {
        const int q = qq*512 + it*16 + qrow;
        float4 imv = *(const float4*)(im + ((size_t)b*2048 + q)*2048 + kk);
        const float rsq = rs[b*2048 + q];
        const float c0 = cmb[q], c1 = cmb[2048+q], c2 = cmb[4096+q], c3 = cmb[6144+q];
        float o[4];
        float iv[4] = {imv.x, imv.y, imv.z, imv.w};
#pragma unroll
        for (int j = 0; j < 4; j++) {
            float same = c0*ck[0][j] + c1*ck[1][j] + c2*ck[2][j] + c3*ck[3][j];
            o[j] = (same*rsq - 0.5f)*2.0f + 0.3f*iv[j];
        }
        *(float4*)(Bias2 + (((size_t)b*512 + kg)*2048 + q)*4) =
            make_float4(o[0], o[1], o[2], o[3]);
    }
}

// ---------------------------------------------------------------------------
// Flash attention, S^T orientation.  q-tile 64 -> 1024 blocks = 4 blocks/CU.
// S 3-term hi/lo; PV single-term: P = truncated-hi bf16 with li computed
// from the SAME truncated weights (systematic bias cancels in O/li), V =
// rounded bf16 (zero-mean error).  Register-prefetch pipelined staging.
// ---------------------------------------------------------------------------
#define KPAD 72   // shorts per K-plane row
#define VPAD 68   // shorts per Vt row

__global__ __launch_bounds__(256, 4)
void attn_mfma(const unsigned* __restrict__ Qp, const unsigned* __restrict__ Kp,
               const short* __restrict__ Vp, const float* __restrict__ Bias2,
               const float* __restrict__ gate, short* __restrict__ Oh,
               short* __restrict__ Ol)
{
    const int bid = blockIdx.x;
    const int h  = bid & 15;
    const int qt = (bid >> 4) & 31;
    const int b  = bid >> 9;

    __shared__ __align__(16) short Kh[64*KPAD];
    __shared__ __align__(16) short Kl[64*KPAD];
    __shared__ __align__(16) short Vt[64*VPAD];   // [d][key], bf16

    const int t    = threadIdx.x;
    const int w    = t >> 6;
    const int lane = t & 63;
    const int col  = lane & 15;
    const int quad = lane >> 4;

    const size_t headoff = ((size_t)(b*16 + h)) * 2048 * 64;
    const unsigned* Qh = Qp + headoff;
    const unsigned* Kg = Kp + headoff;
    const short*    Vg = Vp + headoff;

    const int qb = qt*64 + w*16;        // this wave's 16 q rows

    // ---- Q B-fragments (hi/lo) from packed planes ----
    s8v qfh[2], qfl[2];
#pragma unroll
    for (int c = 0; c < 2; c++) {
        const unsigned* p = Qh + (size_t)(qb + col)*64 + c*32 + quad*8;
        uint4 u0 = *(const uint4*)p;
        uint4 u1 = *(const uint4*)(p + 4);
        unsigned ua[8] = {u0.x,u0.y,u0.z,u0.w, u1.x,u1.y,u1.z,u1.w};
        s8v hi, lo;
#pragma unroll
        for (int j = 0; j < 8; j++) {
            hi[j] = (short)(ua[j] & 0xffffu);
            lo[j] = (short)(ua[j] >> 16);
        }
        qfh[c] = hi; qfl[c] = lo;
    }

    const float g  = fminf(fmaxf(gate[h], 0.f), 1.f);
    const float cS = 0.125f * L2E;
    const float cB = 3.0f * g * L2E;

    float mi = -INFINITY, li = 0.f;
    f4v Oa[4];
#pragma unroll
    for (int dt = 0; dt < 4; dt++) { f4v z = {0.f,0.f,0.f,0.f}; Oa[dt] = z; }

    const int skey = t >> 2;            // staging key 0..63 (K and V)
    const int sc   = t & 3;
    const int vd   = sc * 16;           // V d-segment base

    // ---- prologue: fetch tile 0, stage to LDS ----
    uint4 kr[4];
    s8v   vr[2];
#pragma unroll
    for (int i = 0; i < 4; i++)
        kr[i] = *(const uint4*)(Kg + (size_t)skey*64 + sc*4 + i*16);
    vr[0] = *(const s8v*)(Vg + (size_t)skey*64 + vd);
    vr[1] = *(const s8v*)(Vg + (size_t)skey*64 + vd + 8);
#pragma unroll
    for (int i = 0; i < 4; i++) {
        const int d0 = sc*4 + i*16;
        unsigned ka[4] = {kr[i].x, kr[i].y, kr[i].z, kr[i].w};
        s4v kh4, kl4;
#pragma unroll
        for (int j = 0; j < 4; j++) {
            kh4[j] = (short)(ka[j] & 0xffffu);
            kl4[j] = (short)(ka[j] >> 16);
        }
        *(s4v*)&Kh[skey*KPAD + d0] = kh4;
        *(s4v*)&Kl[skey*KPAD + d0] = kl4;
    }
#pragma unroll
    for (int half = 0; half < 2; half++)
#pragma unroll
        for (int j = 0; j < 8; j++)
            Vt[(vd + half*8 + j)*VPAD + skey] = vr[half][j];
    __syncthreads();

    for (int kt2 = 0; kt2 < 32; kt2++) {
        const int kbase = kt2 * 64;

        // ---- bias loads FIRST (oldest outstanding) ----
        float4 bias[4];
#pragma unroll
        for (int s = 0; s < 4; s++) {
            const int kg = (kbase >> 2) + s*4 + quad;
            bias[s] = *(const float4*)(Bias2 +
                (((size_t)b*512 + kg)*2048 + qb + col)*4);
        }
        // ---- prefetch next K/V tile into registers ----
        if (kt2 < 31) {
            const int nb = kbase + 64;
#pragma unroll
            for (int i = 0; i < 4; i++)
                kr[i] = *(const uint4*)(Kg + (size_t)(nb + skey)*64 + sc*4 + i*16);
            vr[0] = *(const s8v*)(Vg + (size_t)(nb + skey)*64 + vd);
            vr[1] = *(const s8v*)(Vg + (size_t)(nb + skey)*64 + vd + 8);
        }

        // ---- S^T = K·Q^T (3-term hi/lo) ----
        f4v S[4];
#pragma unroll
        for (int s = 0; s < 4; s++) { f4v z = {0.f,0.f,0.f,0.f}; S[s] = z; }
#pragma unroll
        for (int s = 0; s < 4; s++)
#pragma unroll
        for (int c = 0; c < 2; c++) {
            const int off = (s*16 + col)*KPAD + c*32 + quad*8;
            s8v kh = *(const s8v*)&Kh[off];
            s8v kl = *(const s8v*)&Kl[off];
            S[s] = mfma32(kh, qfh[c], S[s]);
            S[s] = mfma32(kh, qfl[c], S[s]);
            S[s] = mfma32(kl, qfh[c], S[s]);
        }

        // ---- bias + online softmax (log2 domain), truncated-hi P ----
#pragma unroll
        for (int s = 0; s < 4; s++) {
            float bv[4] = {bias[s].x, bias[s].y, bias[s].z, bias[s].w};
#pragma unroll
            for (int r = 0; r < 4; r++)
                S[s][r] = S[s][r]*cS + bv[r]*cB;
        }
        float rmax = -INFINITY;
#pragma unroll
        for (int s = 0; s < 4; s++)
#pragma unroll
            for (int r = 0; r < 4; r++) rmax = fmaxf(rmax, S[s][r]);
        rmax = fmaxf(rmax, __shfl_xor(rmax, 16));
        rmax = fmaxf(rmax, __shfl_xor(rmax, 32));
        const float mnew = fmaxf(mi, rmax);
        if (__any(mnew > mi)) {
            const float alpha = exp2f(mi - mnew);
#pragma unroll
            for (int dt = 0; dt < 4; dt++)
#pragma unroll
                for (int r = 0; r < 4; r++) Oa[dt][r] *= alpha;
            li *= alpha;
            mi = mnew;
        }
        s4v ph[4];
        float rsum = 0.f;
#pragma unroll
        for (int s = 0; s < 4; s++) {
            s4v hh;
#pragma unroll
            for (int r = 0; r < 4; r++) {
                float pv = exp2f(S[s][r] - mi);
                union { float f; unsigned u; } uu; uu.f = pv;
                hh[r] = (short)(uu.u >> 16);            // truncated-hi bf16
                union { float f; unsigned u; } tm; tm.u = uu.u & 0xffff0000u;
                rsum += tm.f;                            // li from SAME weights
            }
            ph[s] = hh;
        }
        rsum += __shfl_xor(rsum, 16);
        rsum += __shfl_xor(rsum, 32);
        li += rsum;

        // ---- O^T += V^T·P^T (single term) ----
#pragma unroll
        for (int dt = 0; dt < 4; dt++)
#pragma unroll
        for (int s = 0; s < 4; s++) {
            s4v vh = *(const s4v*)&Vt[(dt*16 + col)*VPAD + s*16 + quad*4];
            Oa[dt] = mfma16x16(vh, ph[s], Oa[dt]);
        }

        // ---- drain compute, then write prefetched tile to LDS ----
        if (kt2 < 31) {
            __syncthreads();
#pragma unroll
            for (int i = 0; i < 4; i++) {
                const int d0 = sc*4 + i*16;
                unsigned ka[4] = {kr[i].x, kr[i].y, kr[i].z, kr[i].w};
                s4v kh4, kl4;
#pragma unroll
                for (int j = 0; j < 4; j++) {
                    kh4[j] = (short)(ka[j] & 0xffffu);
                    kl4[j] = (short)(ka[j] >> 16);
                }
                *(s4v*)&Kh[skey*KPAD + d0] = kh4;
                *(s4v*)&Kl[skey*KPAD + d0] = kl4;
            }
#pragma unroll
            for (int half = 0; half < 2; half++)
#pragma unroll
                for (int j = 0; j < 8; j++)
                    Vt[(vd + half*8 + j)*VPAD + skey] = vr[half][j];
            __syncthreads();
        }
    }

    // ---- epilogue: O^T -> bf16 hi/lo o-planes (B,N,D) ----
    const float inv = 1.0f / li;
    const size_t row = (size_t)b*2048 + qb + col;
#pragma unroll
    for (int dt = 0; dt < 4; dt++) {
        s4v hv, lv;
#pragma unroll
        for (int r = 0; r < 4; r++) {
            float y = Oa[dt][r] * inv;
            unsigned short hb = f2bf(y);
            hv[r] = (short)hb;
            union { float f; unsigned u; } rr; rr.f = y - bf2f(hb);
            lv[r] = (short)(rr.u >> 16);
        }
        const size_t o = row*1024 + h*64 + dt*16 + quad*4;
        *(s4v*)&Oh[o] = hv;
        *(s4v*)&Ol[o] = lv;
    }
}

// ---------------------------------------------------------------------------
extern "C" void kernel_launch(void* const* d_in, const int* in_sizes, int n_in,
                              void* d_out, int out_size, void* d_ws, size_t ws_size,
                              hipStream_t stream)
{
    const float* x    = (const float*)d_in[0];
    const float* cm   = (const float*)d_in[1];
    const float* im   = (const float*)d_in[2];
    const float* Wqkv = (const float*)d_in[3];
    const float* Wout = (const float*)d_in[4];
    const float* qw   = (const float*)d_in[5];
    const float* kw   = (const float*)d_in[6];
    const float* gate = (const float*)d_in[7];
    float* out = (float*)d_out;

    // ---- workspace layout (bytes) ----
    char* ws = (char*)d_ws;
    unsigned* qp  = (unsigned*)(ws);                      // 16.78 MB packed
    unsigned* kp  = (unsigned*)(ws + 16777216);
    short*    vp  = (short*)   (ws + 33554432);           // 8.39 MB bf16
    short*    oh  = (short*)   (ws + 50331648);           // 8.39 MB
    short*    ol  = (short*)   (ws + 58720256);
    short*    woh = (short*)   (ws + 67108864);           // 2.10 MB
    short*    wol = (short*)   (ws + 69206016);
    float*    rsb = (float*)   (ws + 71303168);           // 16 KB
    char*     U   = ws + 71319552;                        // union region
    short*    xh  = (short*)(U);                          // 8.39 MB (dead after gemm0)
    short*    xl  = (short*)(U + 8388608);
    short*    wqh = (short*)(U + 16777216);               // 6.29 MB
    short*    wql = (short*)(U + 23068672);
    float*    bias2 = (float*)(U);                        // 33.55 MB (after gemm0)

    // 1) split inputs into bf16 hi/lo planes
    planes_k<<<4096, 256, 0, stream>>>(x,    xh,  xl);
    planes_k<<<3072, 256, 0, stream>>>(Wqkv, wqh, wql);
    planes_k<<<1024, 256, 0, stream>>>(Wout, woh, wol);
    // 2) qkv projection (MFMA) + fused rmsnorm -> q/k packed, v bf16
    gemm_mfma<0><<<dim3(24, 32), 256, 0, stream>>>(xh, xl, wqh, wql,
                                                   qp, kp, vp, nullptr, qw, kw);
    // 3) bias precompute (overwrites x/wq plane region — dead after gemm0)
    rowscale_k<<<64, 256, 0, stream>>>(cm, rsb);
    bias_pre<<<256, 256, 0, stream>>>(cm, im, rsb, bias2);
    // 4) flash attention -> bf16 o-planes  (1024 blocks = 4/CU)
    attn_mfma<<<1024, 256, 0, stream>>>(qp, kp, vp, bias2, gate, oh, ol);
    // 5) output projection (MFMA) -> fp32 out
    gemm_mfma<1><<<dim3(8, 32), 256, 0, stream>>>(oh, ol, woh, wol,
                                                  nullptr, nullptr, nullptr, out,
                                                  nullptr, nullptr);
}

// Round 7
// 397.830 us; speedup vs baseline: 2.9514x; 1.0262x over previous
//
#include <hip/hip_runtime.h>
#include <math.h>

// Problem constants: B=2, N=2048, D=1024, H=16, HD=64, C=4

typedef __attribute__((ext_vector_type(8))) short s8v;
typedef __attribute__((ext_vector_type(4))) short s4v;
typedef __attribute__((ext_vector_type(4))) float f4v;

#define L2E 1.44269504088896340736f

__device__ __forceinline__ unsigned short f2bf(float x) {
    union { float f; unsigned u; } v; v.f = x;
    unsigned r = v.u + 0x7FFF + ((v.u >> 16) & 1);
    return (unsigned short)(r >> 16);
}
__device__ __forceinline__ float bf2f(unsigned short h) {
    union { unsigned u; float f; } v; v.u = ((unsigned)h) << 16;
    return v.f;
}
__device__ __forceinline__ f4v mfma32(s8v a, s8v b, f4v c) {
    return __builtin_amdgcn_mfma_f32_16x16x32_bf16(a, b, c, 0, 0, 0);
}
__device__ __forceinline__ f4v mfma16x16(s4v a, s4v b, f4v c) {
    return __builtin_amdgcn_mfma_f32_16x16x16bf16_1k(a, b, c, 0, 0, 0);
}
__device__ __forceinline__ void gl_lds16(const void* g, void* l) {
    __builtin_amdgcn_global_load_lds(
        (const __attribute__((address_space(1))) unsigned*)g,
        (__attribute__((address_space(3))) unsigned*)l, 16, 0, 0);
}

// ---------------------------------------------------------------------------
// Split fp32 tensor into bf16 hi/lo planes.
// ---------------------------------------------------------------------------
__global__ __launch_bounds__(256)
void planes_k(const float* __restrict__ src, short* __restrict__ ph,
              short* __restrict__ pl)
{
    const int i = blockIdx.x * 256 + threadIdx.x;
    float4 f = ((const float4*)src)[i];
    float fa[4] = {f.x, f.y, f.z, f.w};
    s4v h4, l4;
#pragma unroll
    for (int j = 0; j < 4; j++) {
        unsigned short hb = f2bf(fa[j]);
        h4[j] = (short)hb;
        l4[j] = (short)f2bf(fa[j] - bf2f(hb));
    }
    ((s4v*)ph)[i] = h4;
    ((s4v*)pl)[i] = l4;
}

// ---------------------------------------------------------------------------
// MFMA GEMM  C[M,NC] = A[M,1024] * B[NC,1024]^T from bf16 hi/lo planes.
// 3-term split.  Tile TM x 128, BK=32 (LDS 32 KB TM128 / 24 KB TM64 -> 3/CU).
// MODE 0 (TM=128): fused RMSNorm (q/k) + scatter -> q/k hi/lo planes, v bf16.
// MODE 1 (TM=64):  plain fp32 row-major Cout.
// ---------------------------------------------------------------------------
template<int MODE, int TM>
__global__ __launch_bounds__(256, 3)
void gemm_mfma(const short* __restrict__ Ah, const short* __restrict__ Al,
               const short* __restrict__ Bh, const short* __restrict__ Bl,
               short* __restrict__ Qhp, short* __restrict__ Qlp,
               short* __restrict__ Khp, short* __restrict__ Klp,
               short* __restrict__ Vp, float* __restrict__ Cout,
               const float* __restrict__ qw, const float* __restrict__ kw)
{
    constexpr int MJ = (TM == 128) ? 4 : 2;
    constexpr int JW = (TM == 128) ? 64 : 32;
    __shared__ short sAh[TM*32], sAl[TM*32], sBh[128*32], sBl[128*32];

    const int t = threadIdx.x, w = t >> 6, lane = t & 63;
    const int col = lane & 15, quad = lane >> 4;
    const int wm = (TM == 128) ? (w >> 1) : 0;
    const int wn = (TM == 128) ? (w & 1) : w;
    const int m0 = blockIdx.y * TM, n0 = blockIdx.x * 128;

    f4v acc[4][MJ];
#pragma unroll
    for (int i = 0; i < 4; i++)
#pragma unroll
        for (int j = 0; j < MJ; j++) { f4v z = {0.f,0.f,0.f,0.f}; acc[i][j] = z; }

    // staging: wave w round j stages rows [(j*4+w)*16, +16); lane: row=lane>>2,
    // chunk=lane&3 XOR (row&3) on source side (conflict-free frag reads).
    const int r4 = lane >> 2;
    const int cs = ((lane & 3) ^ (r4 & 3)) * 8;
    const short* agh = Ah + (size_t)(m0 + w*16 + r4)*1024 + cs;
    const short* agl = Al + (size_t)(m0 + w*16 + r4)*1024 + cs;
    const short* bgh = Bh + (size_t)(n0 + w*16 + r4)*1024 + cs;
    const short* bgl = Bl + (size_t)(n0 + w*16 + r4)*1024 + cs;

    for (int kt = 0; kt < 32; kt++) {
        const int k0 = kt * 32;
        __syncthreads();
#pragma unroll
        for (int j = 0; j < TM/64; j++) {
            gl_lds16(agh + k0 + j*65536, &sAh[(j*4 + w)*512]);
            gl_lds16(agl + k0 + j*65536, &sAl[(j*4 + w)*512]);
        }
#pragma unroll
        for (int j = 0; j < 2; j++) {
            gl_lds16(bgh + k0 + j*65536, &sBh[(j*4 + w)*512]);
            gl_lds16(bgl + k0 + j*65536, &sBl[(j*4 + w)*512]);
        }
        __syncthreads();

        const int swz = ((quad ^ (col & 3)) << 3);
        s8v ahf[4], alf[4], bhf[MJ], blf[MJ];
#pragma unroll
        for (int i = 0; i < 4; i++) {
            const int aoff = (wm*64 + i*16 + col)*32 + swz;
            ahf[i] = *(const s8v*)&sAh[aoff];
            alf[i] = *(const s8v*)&sAl[aoff];
        }
#pragma unroll
        for (int j = 0; j < MJ; j++) {
            const int boff = (wn*JW + j*16 + col)*32 + swz;
            bhf[j] = *(const s8v*)&sBh[boff];
            blf[j] = *(const s8v*)&sBl[boff];
        }
#pragma unroll
        for (int i = 0; i < 4; i++)
#pragma unroll
        for (int j = 0; j < MJ; j++) {
            acc[i][j] = mfma32(ahf[i], bhf[j], acc[i][j]);
            acc[i][j] = mfma32(ahf[i], blf[j], acc[i][j]);
            acc[i][j] = mfma32(alf[i], bhf[j], acc[i][j]);
        }
    }

    if (MODE == 0) {
        // fused RMSNorm over HD=64: each wave holds full 64-col head rows.
        const int whichW = (n0 + wn*64) >> 10;      // wave-uniform: 0=q,1=k,2=v
        if (whichW < 2) {
            const float* nw = (whichW == 0) ? qw : kw;
            float wj[4];
#pragma unroll
            for (int j = 0; j < 4; j++) wj[j] = nw[j*16 + col];
#pragma unroll
            for (int i = 0; i < 4; i++)
#pragma unroll
            for (int r = 0; r < 4; r++) {
                float s2 = acc[i][0][r]*acc[i][0][r] + acc[i][1][r]*acc[i][1][r]
                         + acc[i][2][r]*acc[i][2][r] + acc[i][3][r]*acc[i][3][r];
                s2 += __shfl_xor(s2, 1);
                s2 += __shfl_xor(s2, 2);
                s2 += __shfl_xor(s2, 4);
                s2 += __shfl_xor(s2, 8);
                const float scn = rsqrtf(s2*(1.0f/64.0f) + 1e-6f);
#pragma unroll
                for (int j = 0; j < 4; j++) acc[i][j][r] *= scn*wj[j];
            }
        }
    }

#pragma unroll
    for (int i = 0; i < 4; i++)
#pragma unroll
    for (int j = 0; j < MJ; j++) {
        const int gcol = n0 + wn*JW + j*16 + col;
#pragma unroll
        for (int r = 0; r < 4; r++) {
            const int grow = m0 + wm*64 + i*16 + quad*4 + r;
            const float v = acc[i][j][r];
            if (MODE == 0) {
                const int which = gcol >> 10;
                const int hh = (gcol >> 6) & 15;
                const int hd = gcol & 63;
                const int b = grow >> 11, nn = grow & 2047;
                const size_t idx = ((size_t)(b*16 + hh)*2048 + nn)*64 + hd;
                unsigned short hb = f2bf(v);
                if (which == 2) {
                    Vp[idx] = (short)hb;
                } else {
                    union { float f; unsigned u; } rr; rr.f = v - bf2f(hb);
                    (which == 0 ? Qhp : Khp)[idx] = (short)hb;
                    (which == 0 ? Qlp : Klp)[idx] = (short)(rr.u >> 16);
                }
            } else {
                Cout[(size_t)grow*1024 + gcol] = v;
            }
        }
    }
}

// ---------------------------------------------------------------------------
// rowscale[b,q] = 1 / max(max_k dot4(cm[b,:,q], cm[b,:,k]), 1e-6)
// ---------------------------------------------------------------------------
__global__ __launch_bounds__(256)
void rowscale_k(const float* __restrict__ cm, float* __restrict__ rs)
{
    __shared__ float cms[4][2048];
    const int b  = blockIdx.x >> 5;
    const int qt = blockIdx.x & 31;
    const float* base = cm + (size_t)b * 4 * 2048;
    for (int i = threadIdx.x; i < 2048; i += 256) {
        cms[0][i] = base[i];
        cms[1][i] = base[2048 + i];
        cms[2][i] = base[4096 + i];
        cms[3][i] = base[6144 + i];
    }
    __syncthreads();
    const int q    = qt * 64 + (threadIdx.x >> 2);
    const int part = threadIdx.x & 3;
    const float a0 = cms[0][q], a1 = cms[1][q], a2 = cms[2][q], a3 = cms[3][q];
    float mx = 0.f;
    for (int i = 0; i < 512; i++) {
        const int k = part + 4 * i;
        float d = a0*cms[0][k] + a1*cms[1][k] + a2*cms[2][k] + a3*cms[3][k];
        mx = fmaxf(mx, d);
    }
    mx = fmaxf(mx, __shfl_xor(mx, 1));
    mx = fmaxf(mx, __shfl_xor(mx, 2));
    if (part == 0) rs[b * 2048 + q] = 1.0f / fmaxf(mx, 1e-6f);
}

// ---------------------------------------------------------------------------
// Bias precompute:  Bias2[b][k>>2][q][k&3] = (dot4(cm_q,cm_k)*rsq - 0.5)*2
//                                            + 0.3*im[b][q][k]
// ---------------------------------------------------------------------------
__global__ __launch_bounds__(256)
void bias_pre(const float* __restrict__ cm, const float* __restrict__ im,
              const float* __restrict__ rs, float* __restrict__ Bias2)
{
    const int bid = blockIdx.x;
    const int qq = bid & 3;
    const int kt = (bid >> 2) & 31;
    const int b  = bid >> 7;

    __shared__ float cmk[4][64];
    const int t = threadIdx.x;
    const int k0 = kt * 64;
    cmk[t >> 6][t & 63] = cm[(size_t)b*8192 + (t >> 6)*2048 + k0 + (t & 63)];
    __syncthreads();

    const int klane = t & 15;
    const int qrow  = t >> 4;
    const int kk = k0 + klane*4;
    const int kg = kk >> 2;
    float ck[4][4];
#pragma unroll
    for (int c = 0; c < 4; c++)
#pragma unroll
        for (int j = 0; j < 4; j++) ck[c][j] = cmk[c][klane*4 + j];

    const float* cmb = cm + (size_t)b * 8192;
    for (int it = 0; it < 32; it++) {
        const int q = qq*512 + it*16 + qrow;
        float4 imv = *(const float4*)(im + ((size_t)b*2048 + q)*2048 + kk);
        const float rsq = rs[b*2048 + q];
        const float c0 = cmb[q], c1 = cmb[2048+q], c2 = cmb[4096+q], c3 = cmb[6144+q];
        float o[4];
        float iv[4] = {imv.x, imv.y, imv.z, imv.w};
#pragma unroll
        for (int j = 0; j < 4; j++) {
            float same = c0*ck[0][j] + c1*ck[1][j] + c2*ck[2][j] + c3*ck[3][j];
            o[j] = (same*rsq - 0.5f)*2.0f + 0.3f*iv[j];
        }
        *(float4*)(Bias2 + (((size_t)b*512 + kg)*2048 + q)*4) =
            make_float4(o[0], o[1], o[2], o[3]);
    }
}

// ---------------------------------------------------------------------------
// Flash attention, S^T orientation.  q-tile 128 (32 q/wave), 512 blocks,
// 2 blocks/CU.  K staged by global_load_lds DMA (double-buffered, unpadded,
// XOR source swizzle); V register-prefetched into transposed bf16 LDS tile;
// bias double-buffered in registers one tile ahead (ping-pong, 2x unroll).
// All global latency sits a full compute-phase before its drain.
// ---------------------------------------------------------------------------
#define VPAD 68

__global__ __launch_bounds__(256, 2)
void attn_mfma(const short* __restrict__ Qhp, const short* __restrict__ Qlp,
               const short* __restrict__ Khg, const short* __restrict__ Klg,
               const short* __restrict__ Vg0, const float* __restrict__ Bias2,
               const float* __restrict__ gate, short* __restrict__ Oh,
               short* __restrict__ Ol)
{
    const int bid = blockIdx.x;
    const int h  = bid & 15;
    const int qt = (bid >> 4) & 15;
    const int b  = bid >> 8;

    __shared__ __align__(16) short Kbuf[2][2][64*64];   // [pp][hi/lo][key][d] swizzled
    __shared__ __align__(16) short Vt[64*VPAD];         // [d][key] bf16

    const int t    = threadIdx.x;
    const int w    = t >> 6;
    const int lane = t & 63;
    const int col  = lane & 15;
    const int quad = lane >> 4;

    const size_t headoff = ((size_t)(b*16 + h)) * 2048 * 64;
    const int qb = qt*128 + w*32;

    // ---- Q B-fragments (hi/lo) straight from planes ----
    s8v qfh[2][2], qfl[2][2];
#pragma unroll
    for (int n = 0; n < 2; n++)
#pragma unroll
    for (int c = 0; c < 2; c++) {
        const size_t off = headoff + (size_t)(qb + n*16 + col)*64 + c*32 + quad*8;
        qfh[n][c] = *(const s8v*)(Qhp + off);
        qfl[n][c] = *(const s8v*)(Qlp + off);
    }

    const float g  = fminf(fmaxf(gate[h], 0.f), 1.f);
    const float cS = 0.125f * L2E;
    const float cB = 3.0f * g * L2E;

    float mi[2] = {-INFINITY, -INFINITY};
    float li[2] = {0.f, 0.f};
    f4v Oa[4][2];
#pragma unroll
    for (int dt = 0; dt < 4; dt++)
#pragma unroll
        for (int n = 0; n < 2; n++) { f4v z = {0.f,0.f,0.f,0.f}; Oa[dt][n] = z; }

    // ---- staging bases ----
    const short* ksrc_h = Khg + headoff + (size_t)(w*8 + (lane>>3))*64
                          + ((lane&7) ^ (lane>>3))*8;
    const short* ksrc_l = Klg + headoff + (size_t)(w*8 + (lane>>3))*64
                          + ((lane&7) ^ (lane>>3))*8;
    const int skey = t >> 2;
    const int sc   = t & 3;
    const short* vsrc = Vg0 + headoff + (size_t)skey*64 + sc*16;

    const float* bptr[2];
#pragma unroll
    for (int n = 0; n < 2; n++)
        bptr[n] = Bias2 + (((size_t)b*512 + quad)*2048 + qb + n*16 + col)*4;

    auto dma = [&](int kbase, int pp) {
#pragma unroll
        for (int j = 0; j < 2; j++) {
            gl_lds16(ksrc_h + (size_t)kbase*64 + j*2048, &Kbuf[pp][0][(j*4 + w)*512]);
            gl_lds16(ksrc_l + (size_t)kbase*64 + j*2048, &Kbuf[pp][1][(j*4 + w)*512]);
        }
    };
    auto writeV = [&](s8v vr0, s8v vr1) {
#pragma unroll
        for (int j = 0; j < 8; j++) Vt[(sc*16 + j)*VPAD + skey]     = vr0[j];
#pragma unroll
        for (int j = 0; j < 8; j++) Vt[(sc*16 + 8 + j)*VPAD + skey] = vr1[j];
    };

    float4 biasA[4][2], biasB[4][2];

    // ---- prologue: tile 0 ----
    dma(0, 0);
    {
        s8v vr0 = *(const s8v*)(vsrc);
        s8v vr1 = *(const s8v*)(vsrc + 8);
#pragma unroll
        for (int s = 0; s < 4; s++)
#pragma unroll
        for (int n = 0; n < 2; n++)
            biasA[s][n] = *(const float4*)(bptr[n] + (size_t)s*4*8192);
        writeV(vr0, vr1);
    }
    __syncthreads();

    auto tile = [&](int kt, int pp, float4 (&BC)[4][2], float4 (&BN)[4][2]) {
        const int kbase = kt * 64;
        const bool pre = kt < 31;
        s8v vr0, vr1;
        if (pre) {
            // bias for kt+1 (oldest outstanding)
#pragma unroll
            for (int s = 0; s < 4; s++)
#pragma unroll
            for (int n = 0; n < 2; n++)
                BN[s][n] = *(const float4*)(bptr[n] +
                    ((size_t)((kbase >> 2) + 16) + s*4)*8192);
            dma(kbase + 64, pp ^ 1);
            vr0 = *(const s8v*)(vsrc + (size_t)(kbase + 64)*64);
            vr1 = *(const s8v*)(vsrc + (size_t)(kbase + 64)*64 + 8);
        }

        // ---- S^T = K·Q^T (3-term hi/lo) ----
        f4v S[4][2];
#pragma unroll
        for (int s = 0; s < 4; s++)
#pragma unroll
            for (int n = 0; n < 2; n++) { f4v z = {0.f,0.f,0.f,0.f}; S[s][n] = z; }
#pragma unroll
        for (int s = 0; s < 4; s++)
#pragma unroll
        for (int c = 0; c < 2; c++) {
            const int koff = (s*16 + col)*64 + (((c*4 + quad) ^ (col & 7)) << 3);
            s8v kh = *(const s8v*)&Kbuf[pp][0][koff];
            s8v kl = *(const s8v*)&Kbuf[pp][1][koff];
#pragma unroll
            for (int n = 0; n < 2; n++) {
                S[s][n] = mfma32(kh, qfh[n][c], S[s][n]);
                S[s][n] = mfma32(kh, qfl[n][c], S[s][n]);
                S[s][n] = mfma32(kl, qfh[n][c], S[s][n]);
            }
        }

        // ---- bias + online softmax (log2 domain), truncated-hi P ----
        s4v ph[2][4];
#pragma unroll
        for (int n = 0; n < 2; n++) {
            float sr[4][4];
            float rmax = -INFINITY;
#pragma unroll
            for (int s = 0; s < 4; s++) {
                float bv[4] = {BC[s][n].x, BC[s][n].y, BC[s][n].z, BC[s][n].w};
#pragma unroll
                for (int r = 0; r < 4; r++) {
                    sr[s][r] = S[s][n][r]*cS + bv[r]*cB;
                    rmax = fmaxf(rmax, sr[s][r]);
                }
            }
            rmax = fmaxf(rmax, __shfl_xor(rmax, 16));
            rmax = fmaxf(rmax, __shfl_xor(rmax, 32));
            const float mnew = fmaxf(mi[n], rmax);
            if (__any(mnew > mi[n])) {
                const float alpha = exp2f(mi[n] - mnew);
#pragma unroll
                for (int dt = 0; dt < 4; dt++)
#pragma unroll
                    for (int r = 0; r < 4; r++) Oa[dt][n][r] *= alpha;
                li[n] *= alpha;
                mi[n] = mnew;
            }
            float rsum = 0.f;
#pragma unroll
            for (int s = 0; s < 4; s++) {
                s4v hh;
#pragma unroll
                for (int r = 0; r < 4; r++) {
                    float pv = exp2f(sr[s][r] - mi[n]);
                    union { float f; unsigned u; } uu; uu.f = pv;
                    hh[r] = (short)(uu.u >> 16);            // truncated-hi bf16
                    union { float f; unsigned u; } tm; tm.u = uu.u & 0xffff0000u;
                    rsum += tm.f;                            // li from SAME weights
                }
                ph[n][s] = hh;
            }
            rsum += __shfl_xor(rsum, 16);
            rsum += __shfl_xor(rsum, 32);
            li[n] += rsum;
        }

        // ---- O^T += V^T·P^T (single term) ----
#pragma unroll
        for (int dt = 0; dt < 4; dt++)
#pragma unroll
        for (int s = 0; s < 4; s++) {
            s4v vh = *(const s4v*)&Vt[(dt*16 + col)*VPAD + s*16 + quad*4];
#pragma unroll
            for (int n = 0; n < 2; n++)
                Oa[dt][n] = mfma16x16(vh, ph[n][s], Oa[dt][n]);
        }

        if (pre) {
            __syncthreads();            // all waves done reading Vt (+ drains)
            writeV(vr0, vr1);
            __syncthreads();            // V visible; own DMA drained -> K pp^1 ready
        }
    };

    for (int kt = 0; kt < 32; kt += 2) {
        tile(kt,     0, biasA, biasB);
        tile(kt + 1, 1, biasB, biasA);
    }

    // ---- epilogue: O^T -> bf16 hi/lo o-planes (B,N,D) ----
#pragma unroll
    for (int n = 0; n < 2; n++) {
        const float inv = 1.0f / li[n];
        const size_t row = (size_t)b*2048 + qb + n*16 + col;
#pragma unroll
        for (int dt = 0; dt < 4; dt++) {
            s4v hv, lv;
#pragma unroll
            for (int r = 0; r < 4; r++) {
                float y = Oa[dt][n][r] * inv;
                unsigned short hb = f2bf(y);
                hv[r] = (short)hb;
                union { float f; unsigned u; } rr; rr.f = y - bf2f(hb);
                lv[r] = (short)(rr.u >> 16);
            }
            const size_t o = row*1024 + h*64 + dt*16 + quad*4;
            *(s4v*)&Oh[o] = hv;
            *(s4v*)&Ol[o] = lv;
        }
    }
}

// ---------------------------------------------------------------------------
extern "C" void kernel_launch(void* const* d_in, const int* in_sizes, int n_in,
                              void* d_out, int out_size, void* d_ws, size_t ws_size,
                              hipStream_t stream)
{
    const float* x    = (const float*)d_in[0];
    const float* cm   = (const float*)d_in[1];
    const float* im   = (const float*)d_in[2];
    const float* Wqkv = (const float*)d_in[3];
    const float* Wout = (const float*)d_in[4];
    const float* qw   = (const float*)d_in[5];
    const float* kw   = (const float*)d_in[6];
    const float* gate = (const float*)d_in[7];
    float* out = (float*)d_out;

    // ---- workspace layout (bytes) ----
    char* ws = (char*)d_ws;
    short* qhp = (short*)(ws);                    // 8.39 MB each
    short* qlp = (short*)(ws +  8388608);
    short* khp = (short*)(ws + 16777216);
    short* klp = (short*)(ws + 25165824);
    short* vp  = (short*)(ws + 33554432);
    short* oh  = (short*)(ws + 41943040);
    short* ol  = (short*)(ws + 50331648);
    short* woh = (short*)(ws + 58720256);         // 2.10 MB each
    short* wol = (short*)(ws + 60817408);
    float* rsb = (float*)(ws + 62914560);         // 16 KB
    char*  U   = ws + 62930944;                   // union region
    short* xh  = (short*)(U);                     // 8.39 MB (dead after gemm0)
    short* xl  = (short*)(U +  8388608);
    short* wqh = (short*)(U + 16777216);          // 6.29 MB
    short* wql = (short*)(U + 23068672);
    float* bias2 = (float*)(U);                   // 33.55 MB (after gemm0)

    // 1) split inputs into bf16 hi/lo planes
    planes_k<<<4096, 256, 0, stream>>>(x,    xh,  xl);
    planes_k<<<3072, 256, 0, stream>>>(Wqkv, wqh, wql);
    planes_k<<<1024, 256, 0, stream>>>(Wout, woh, wol);
    // 2) qkv projection (MFMA) + fused rmsnorm -> q/k hi/lo planes, v bf16
    gemm_mfma<0,128><<<dim3(24, 32), 256, 0, stream>>>(xh, xl, wqh, wql,
        qhp, qlp, khp, klp, vp, nullptr, qw, kw);
    // 3) bias precompute (overwrites x/wq plane region — dead after gemm0)
    rowscale_k<<<64, 256, 0, stream>>>(cm, rsb);
    bias_pre<<<256, 256, 0, stream>>>(cm, im, rsb, bias2);
    // 4) flash attention -> bf16 o-planes  (512 blocks = 2/CU, q-tile 128)
    attn_mfma<<<512, 256, 0, stream>>>(qhp, qlp, khp, klp, vp, bias2, gate,
                                       oh, ol);
    // 5) output projection (MFMA, 64-row tiles -> 512 blocks) -> fp32 out
    gemm_mfma<1,64><<<dim3(8, 64), 256, 0, stream>>>(oh, ol, woh, wol,
        nullptr, nullptr, nullptr, nullptr, nullptr, out, nullptr, nullptr);
}